// Round 1
// baseline (2773.639 us; speedup 1.0000x reference)
//
#include <hip/hip_runtime.h>

// Problem constants (B,S,D,H fixed by the reference)
#define Bsz 4
#define Ssz 2048
#define Dsz 1024
#define Hsz 4
#define HDsz 256
#define Msz 8192  // Bsz*Ssz

// ---------------------------------------------------------------------------
// GEMM: C[M,N] = A(M,K) * B[N,K]^T (+bias).  M=8192, N=K=1024.
// 128x128 tile, BK=16, 256 threads, 8x8 micro-tile.
// BHSE=true: A is the blend buffer in [b][h][s][e] layout (k = h*256+e).
// ---------------------------------------------------------------------------
template <bool BHSE>
__global__ __launch_bounds__(256) void gemm_nt(const float* __restrict__ A,
                                               const float* __restrict__ Bm,
                                               const float* __restrict__ bias,
                                               float* __restrict__ C) {
  __shared__ float As[16][132];  // [k][m], pad 132 keeps float4 alignment, 2-way conflicts only
  __shared__ float Bs[16][132];  // [k][n]
  const int tid = threadIdx.x;
  const int tx = tid & 15, ty = tid >> 4;
  const int m0 = blockIdx.y * 128, n0 = blockIdx.x * 128;
  float acc[8][8] = {};
  for (int k0 = 0; k0 < Dsz; k0 += 16) {
#pragma unroll
    for (int i = 0; i < 2; ++i) {
      int f4 = i * 256 + tid;       // 0..511 : 128 rows x 4 float4
      int row = f4 >> 2, c4 = f4 & 3;
      const float* ap;
      if (BHSE) {
        int m = m0 + row, b = m >> 11, s = m & 2047;
        int h = k0 >> 8, e0 = k0 & 255;  // 16-wide k-tile never crosses a head
        ap = A + ((size_t)((b << 2) + h) * Ssz + s) * HDsz + e0 + c4 * 4;
      } else {
        ap = A + (size_t)(m0 + row) * Dsz + k0 + c4 * 4;
      }
      float4 v = *(const float4*)ap;
      As[c4 * 4 + 0][row] = v.x; As[c4 * 4 + 1][row] = v.y;
      As[c4 * 4 + 2][row] = v.z; As[c4 * 4 + 3][row] = v.w;
      const float* bp = Bm + (size_t)(n0 + row) * Dsz + k0 + c4 * 4;
      float4 w = *(const float4*)bp;
      Bs[c4 * 4 + 0][row] = w.x; Bs[c4 * 4 + 1][row] = w.y;
      Bs[c4 * 4 + 2][row] = w.z; Bs[c4 * 4 + 3][row] = w.w;
    }
    __syncthreads();
#pragma unroll
    for (int k = 0; k < 16; ++k) {
      float a[8], b[8];
      *(float4*)(a) = *(const float4*)(&As[k][ty * 8]);
      *(float4*)(a + 4) = *(const float4*)(&As[k][ty * 8 + 4]);
      *(float4*)(b) = *(const float4*)(&Bs[k][tx * 8]);
      *(float4*)(b + 4) = *(const float4*)(&Bs[k][tx * 8 + 4]);
#pragma unroll
      for (int i = 0; i < 8; ++i)
#pragma unroll
        for (int j = 0; j < 8; ++j) acc[i][j] = fmaf(a[i], b[j], acc[i][j]);
    }
    __syncthreads();
  }
#pragma unroll
  for (int i = 0; i < 8; ++i) {
    int m = m0 + ty * 8 + i;
    float* cp = C + (size_t)m * Dsz + n0 + tx * 8;
    float4 o0, o1;
    o0.x = acc[i][0]; o0.y = acc[i][1]; o0.z = acc[i][2]; o0.w = acc[i][3];
    o1.x = acc[i][4]; o1.y = acc[i][5]; o1.z = acc[i][6]; o1.w = acc[i][7];
    if (bias) {
      const float* bb = bias + n0 + tx * 8;
      o0.x += bb[0]; o0.y += bb[1]; o0.z += bb[2]; o0.w += bb[3];
      o1.x += bb[4]; o1.y += bb[5]; o1.z += bb[6]; o1.w += bb[7];
    }
    *(float4*)cp = o0;
    *(float4*)(cp + 4) = o1;
  }
}

// ---------------------------------------------------------------------------
// Causal attention (no 1/sqrt(d) scale, faithful to reference).
// Flash-style: Br=16 queries/block, Bc=32 keys/tile, online softmax held in
// registers (16-lane shfl groups), K and V share one LDS buffer.
// grid = (S/16, B*H), 256 threads. attn out layout: [b][h][s][e].
// ---------------------------------------------------------------------------
__global__ __launch_bounds__(256) void attn_kernel(const float* __restrict__ Q,
                                                   const float* __restrict__ K,
                                                   const float* __restrict__ V,
                                                   float* __restrict__ attn) {
  const int qt = blockIdx.x;                // 0..127
  const int bh = blockIdx.y;                // b*H+h
  const int b = bh >> 2, h = bh & 3;
  const int tid = threadIdx.x;
  const int tq = tid >> 4;                  // 0..15 query row
  const int tw = tid & 15;                  // 0..15 key / dim-slice lane
  __shared__ float Qs[16][260];             // pitch 260: 4-bank row stagger
  __shared__ float KVs[32][260];            // shared K then V buffer
  const int q0 = qt * 16;
  const float* qbase = Q + ((size_t)b * Ssz + q0) * Dsz + h * HDsz;
#pragma unroll
  for (int i = 0; i < 4; ++i) {
    int f4 = i * 256 + tid;                 // 16 rows x 64 f4
    int row = f4 >> 6, c4 = f4 & 63;
    *(float4*)(&Qs[row][c4 * 4]) = *(const float4*)(qbase + (size_t)row * Dsz + c4 * 4);
  }
  float O[4][4] = {};                       // dims: float4 index ii*16+tw
  float m_old = -1e30f, l = 0.f;
  const int qg = q0 + tq;
  const int ktmax = qt >> 1;
  for (int kt = 0; kt <= ktmax; ++kt) {
    const int j0 = kt * 32;
    __syncthreads();                        // KVs free (prev PV done) / Qs loaded
    const float* kbase = K + ((size_t)b * Ssz + j0) * Dsz + h * HDsz;
#pragma unroll
    for (int i = 0; i < 8; ++i) {
      int f4 = i * 256 + tid;
      int row = f4 >> 6, c4 = f4 & 63;
      *(float4*)(&KVs[row][c4 * 4]) = *(const float4*)(kbase + (size_t)row * Dsz + c4 * 4);
    }
    __syncthreads();
    float s0 = 0.f, s1 = 0.f;               // keys j0+tw, j0+tw+16
    for (int kk = 0; kk < 64; ++kk) {
      float4 qv = *(const float4*)(&Qs[tq][kk * 4]);
      float4 k0v = *(const float4*)(&KVs[tw][kk * 4]);
      float4 k1v = *(const float4*)(&KVs[tw + 16][kk * 4]);
      s0 += qv.x * k0v.x + qv.y * k0v.y + qv.z * k0v.z + qv.w * k0v.w;
      s1 += qv.x * k1v.x + qv.y * k1v.y + qv.z * k1v.z + qv.w * k1v.w;
    }
    if (j0 + tw > qg) s0 = -1e30f;          // causal mask
    if (j0 + tw + 16 > qg) s1 = -1e30f;
    __syncthreads();                        // done reading K
    const float* vbase = V + ((size_t)b * Ssz + j0) * Dsz + h * HDsz;
#pragma unroll
    for (int i = 0; i < 8; ++i) {
      int f4 = i * 256 + tid;
      int row = f4 >> 6, c4 = f4 & 63;
      *(float4*)(&KVs[row][c4 * 4]) = *(const float4*)(vbase + (size_t)row * Dsz + c4 * 4);
    }
    // online softmax bookkeeping in registers (overlaps V load latency)
    float mx = fmaxf(s0, s1);
#pragma unroll
    for (int off = 1; off < 16; off <<= 1) mx = fmaxf(mx, __shfl_xor(mx, off));
    float m_new = fmaxf(m_old, mx);
    float alpha = __expf(m_old - m_new);
    float p0 = __expf(s0 - m_new), p1 = __expf(s1 - m_new);
    float ps = p0 + p1;
#pragma unroll
    for (int off = 1; off < 16; off <<= 1) ps += __shfl_xor(ps, off);
    l = l * alpha + ps;
    m_old = m_new;
#pragma unroll
    for (int ii = 0; ii < 4; ++ii)
#pragma unroll
      for (int c = 0; c < 4; ++c) O[ii][c] *= alpha;
    __syncthreads();                        // V tile visible
#pragma unroll 4
    for (int j = 0; j < 16; ++j) {
      float pj = __shfl(p0, (tid & 48) | j);
#pragma unroll
      for (int ii = 0; ii < 4; ++ii) {
        float4 vv = *(const float4*)(&KVs[j][(ii * 16 + tw) * 4]);
        O[ii][0] += pj * vv.x; O[ii][1] += pj * vv.y;
        O[ii][2] += pj * vv.z; O[ii][3] += pj * vv.w;
      }
    }
#pragma unroll 4
    for (int j = 0; j < 16; ++j) {
      float pj = __shfl(p1, (tid & 48) | j);
#pragma unroll
      for (int ii = 0; ii < 4; ++ii) {
        float4 vv = *(const float4*)(&KVs[j + 16][(ii * 16 + tw) * 4]);
        O[ii][0] += pj * vv.x; O[ii][1] += pj * vv.y;
        O[ii][2] += pj * vv.z; O[ii][3] += pj * vv.w;
      }
    }
  }
  float linv = 1.f / l;
  float* obase = attn + ((size_t)bh * Ssz + q0 + tq) * HDsz;
#pragma unroll
  for (int ii = 0; ii < 4; ++ii) {
    float4 vv = make_float4(O[ii][0] * linv, O[ii][1] * linv, O[ii][2] * linv, O[ii][3] * linv);
    *(float4*)(obase + (ii * 16 + tw) * 4) = vv;
  }
}

// ---------------------------------------------------------------------------
// sq = elu(q)+1 (= q+1 if q>0 else exp(q)), in-place on Q and K buffers.
// grid 8192 x 256, one float4 per thread per buffer.
// ---------------------------------------------------------------------------
__global__ __launch_bounds__(256) void elu1_kernel(float4* __restrict__ Q4,
                                                   float4* __restrict__ K4) {
  size_t i = (size_t)blockIdx.x * 256 + threadIdx.x;
  float4 q = Q4[i];
  q.x = q.x > 0.f ? q.x + 1.f : __expf(q.x);
  q.y = q.y > 0.f ? q.y + 1.f : __expf(q.y);
  q.z = q.z > 0.f ? q.z + 1.f : __expf(q.z);
  q.w = q.w > 0.f ? q.w + 1.f : __expf(q.w);
  Q4[i] = q;
  float4 k = K4[i];
  k.x = k.x > 0.f ? k.x + 1.f : __expf(k.x);
  k.y = k.y > 0.f ? k.y + 1.f : __expf(k.y);
  k.z = k.z > 0.f ? k.z + 1.f : __expf(k.z);
  k.w = k.w > 0.f ? k.w + 1.f : __expf(k.w);
  K4[i] = k;
}

// ---------------------------------------------------------------------------
// denq[r] = sq_row . z[h],  denk[r] = sk_row . z[h],  r = (b*H+h)*S+s.
// One wave per row; grid 8192 x 256 (4 waves/block).
// ---------------------------------------------------------------------------
__global__ __launch_bounds__(256) void dens_kernel(const float* __restrict__ SQ,
                                                   const float* __restrict__ SK,
                                                   const float* __restrict__ z,
                                                   float* __restrict__ denq,
                                                   float* __restrict__ denk) {
  const int wid = threadIdx.x >> 6, lane = threadIdx.x & 63;
  const int r = blockIdx.x * 4 + wid;       // 0..32767
  const int b = r >> 13, h = (r >> 11) & 3, s = r & 2047;
  const size_t base = ((size_t)(b * Ssz + s)) * Dsz + h * HDsz + lane * 4;
  float4 zq = *(const float4*)(z + h * HDsz + lane * 4);
  float4 q4 = *(const float4*)(SQ + base);
  float4 k4 = *(const float4*)(SK + base);
  float pq = q4.x * zq.x + q4.y * zq.y + q4.z * zq.z + q4.w * zq.w;
  float pk = k4.x * zq.x + k4.y * zq.y + k4.z * zq.z + k4.w * zq.w;
#pragma unroll
  for (int off = 32; off; off >>= 1) {
    pq += __shfl_down(pq, off);
    pk += __shfl_down(pk, off);
  }
  if (lane == 0) { denq[r] = pq; denk[r] = pk; }
}

// ---------------------------------------------------------------------------
// Per-head NN GEMM: acc[m,e] = sum_d Asrc[m, h*256+d] * mem[h][d][e].
// mode 0: io = attn buffer ([b][h][s][e]); write blend = g*acc/(den)+ (1-g)*attn
// mode 1: io = V buffer ([m][1024]);       write W = v - acc/(den)
// grid (2, 64, 4) : (e-tiles, m-tiles, heads)
// ---------------------------------------------------------------------------
__global__ __launch_bounds__(256) void memread_gemm(const float* __restrict__ Asrc,
                                                    const float* __restrict__ mem,
                                                    const float* __restrict__ dens,
                                                    const float* __restrict__ betas,
                                                    float* __restrict__ io, int mode) {
  const int h = blockIdx.z;
  const int tid = threadIdx.x, tx = tid & 15, ty = tid >> 4;
  const int m0 = blockIdx.y * 128, n0 = blockIdx.x * 128;
  __shared__ float As[16][132];  // [k=d][m]
  __shared__ float Bs[16][132];  // [k=d][e]
  float acc[8][8] = {};
  for (int k0 = 0; k0 < HDsz; k0 += 16) {
#pragma unroll
    for (int i = 0; i < 2; ++i) {
      int f4 = i * 256 + tid;
      {
        int row = f4 >> 2, c4 = f4 & 3;
        float4 v = *(const float4*)(Asrc + (size_t)(m0 + row) * Dsz + h * HDsz + k0 + c4 * 4);
        As[c4 * 4 + 0][row] = v.x; As[c4 * 4 + 1][row] = v.y;
        As[c4 * 4 + 2][row] = v.z; As[c4 * 4 + 3][row] = v.w;
      }
      {
        int k = f4 >> 5, e4 = f4 & 31;
        float4 v = *(const float4*)(mem + (size_t)h * 65536 + (size_t)(k0 + k) * HDsz + n0 + e4 * 4);
        *(float4*)(&Bs[k][e4 * 4]) = v;
      }
    }
    __syncthreads();
#pragma unroll
    for (int k = 0; k < 16; ++k) {
      float a[8], b[8];
      *(float4*)(a) = *(const float4*)(&As[k][ty * 8]);
      *(float4*)(a + 4) = *(const float4*)(&As[k][ty * 8 + 4]);
      *(float4*)(b) = *(const float4*)(&Bs[k][tx * 8]);
      *(float4*)(b + 4) = *(const float4*)(&Bs[k][tx * 8 + 4]);
#pragma unroll
      for (int i = 0; i < 8; ++i)
#pragma unroll
        for (int j = 0; j < 8; ++j) acc[i][j] = fmaf(a[i], b[j], acc[i][j]);
    }
    __syncthreads();
  }
  const float g = 1.f / (1.f + __expf(-betas[h]));
#pragma unroll
  for (int i = 0; i < 8; ++i) {
    int m = m0 + ty * 8 + i;
    int b = m >> 11, s = m & 2047;
    int rowidx = ((b << 2) + h) * Ssz + s;
    float inv = 1.f / (dens[rowidx] + 1e-6f);
    if (mode == 0) {
      float* p = io + (size_t)rowidx * HDsz + n0 + tx * 8;
      float4 a0 = *(float4*)p, a1 = *(float4*)(p + 4);
      float4 o0, o1;
      o0.x = g * acc[i][0] * inv + (1.f - g) * a0.x;
      o0.y = g * acc[i][1] * inv + (1.f - g) * a0.y;
      o0.z = g * acc[i][2] * inv + (1.f - g) * a0.z;
      o0.w = g * acc[i][3] * inv + (1.f - g) * a0.w;
      o1.x = g * acc[i][4] * inv + (1.f - g) * a1.x;
      o1.y = g * acc[i][5] * inv + (1.f - g) * a1.y;
      o1.z = g * acc[i][6] * inv + (1.f - g) * a1.z;
      o1.w = g * acc[i][7] * inv + (1.f - g) * a1.w;
      *(float4*)p = o0;
      *(float4*)(p + 4) = o1;
    } else {
      float* p = io + (size_t)m * Dsz + h * HDsz + n0 + tx * 8;
      float4 v0 = *(float4*)p, v1 = *(float4*)(p + 4);
      float4 o0, o1;
      o0.x = v0.x - acc[i][0] * inv; o0.y = v0.y - acc[i][1] * inv;
      o0.z = v0.z - acc[i][2] * inv; o0.w = v0.w - acc[i][3] * inv;
      o1.x = v1.x - acc[i][4] * inv; o1.y = v1.y - acc[i][5] * inv;
      o1.z = v1.z - acc[i][6] * inv; o1.w = v1.w - acc[i][7] * inv;
      *(float4*)p = o0;
      *(float4*)(p + 4) = o1;
    }
  }
}

// ---------------------------------------------------------------------------
// mem_new[h][d][e] = mem[h][d][e] + (1/B) sum_m sk[m, h*256+d] * W[m, h*256+e]
// TN GEMM, split-K into 16 chunks of 512 rows, atomicAdd into zeroed output.
// grid (2, 2, 64): (e-tile, d-tile, h*16+chunk)
// ---------------------------------------------------------------------------
__global__ __launch_bounds__(256) void mem_update(const float* __restrict__ SK,
                                                  const float* __restrict__ W,
                                                  const float* __restrict__ mem,
                                                  float* __restrict__ outmem) {
  const int h = blockIdx.z >> 4, chunk = blockIdx.z & 15;
  const int d0 = blockIdx.y * 128, e0 = blockIdx.x * 128;
  const int m0 = chunk * 512;
  const int tid = threadIdx.x, tx = tid & 15, ty = tid >> 4;
  __shared__ float As[16][132];  // [m][d]
  __shared__ float Bs[16][132];  // [m][e]
  float acc[8][8] = {};
  for (int mt = 0; mt < 512; mt += 16) {
#pragma unroll
    for (int i = 0; i < 2; ++i) {
      int f4 = i * 256 + tid;
      int mi = f4 >> 5, c4 = f4 & 31;
      size_t rb = (size_t)(m0 + mt + mi) * Dsz + h * HDsz;
      *(float4*)(&As[mi][c4 * 4]) = *(const float4*)(SK + rb + d0 + c4 * 4);
      *(float4*)(&Bs[mi][c4 * 4]) = *(const float4*)(W + rb + e0 + c4 * 4);
    }
    __syncthreads();
#pragma unroll
    for (int k = 0; k < 16; ++k) {
      float a[8], b[8];
      *(float4*)(a) = *(const float4*)(&As[k][ty * 8]);
      *(float4*)(a + 4) = *(const float4*)(&As[k][ty * 8 + 4]);
      *(float4*)(b) = *(const float4*)(&Bs[k][tx * 8]);
      *(float4*)(b + 4) = *(const float4*)(&Bs[k][tx * 8 + 4]);
#pragma unroll
      for (int i = 0; i < 8; ++i)
#pragma unroll
        for (int j = 0; j < 8; ++j) acc[i][j] = fmaf(a[i], b[j], acc[i][j]);
    }
    __syncthreads();
  }
#pragma unroll
  for (int i = 0; i < 8; ++i) {
    int d = d0 + ty * 8 + i;
#pragma unroll
    for (int j = 0; j < 8; ++j) {
      int e = e0 + tx * 8 + j;
      float val = acc[i][j] * 0.25f;  // 1/B
      size_t idx = (size_t)h * 65536 + (size_t)d * HDsz + e;
      if (chunk == 0) val += mem[idx];
      atomicAdd(outmem + idx, val);
    }
  }
}

// ---------------------------------------------------------------------------
// z_new[h][d] = z[h][d] + (1/B) sum_{b,s} sk[b,h,s,d]
// grid 64 (h*16+chunk), 256 threads (one per d), atomicAdd into zeroed output.
// ---------------------------------------------------------------------------
__global__ __launch_bounds__(256) void z_update(const float* __restrict__ SK,
                                                const float* __restrict__ z_in,
                                                float* __restrict__ z_out) {
  const int h = blockIdx.x >> 4, chunk = blockIdx.x & 15;
  const int t = threadIdx.x;
  const int m0 = chunk * 512;
  float sum = 0.f;
  for (int i = 0; i < 512; ++i) sum += SK[(size_t)(m0 + i) * Dsz + h * HDsz + t];
  float val = sum * 0.25f;
  if (chunk == 0) val += z_in[h * HDsz + t];
  atomicAdd(z_out + h * HDsz + t, val);
}

// ---------------------------------------------------------------------------
extern "C" void kernel_launch(void* const* d_in, const int* in_sizes, int n_in,
                              void* d_out, int out_size, void* d_ws, size_t ws_size,
                              hipStream_t stream) {
  (void)in_sizes; (void)n_in; (void)out_size; (void)ws_size;
  const float* Hs = (const float*)d_in[0];
  const float* Wq = (const float*)d_in[1];
  const float* Wk = (const float*)d_in[2];
  const float* Wv = (const float*)d_in[3];
  const float* Wo = (const float*)d_in[4];
  const float* bo = (const float*)d_in[5];
  const float* betas = (const float*)d_in[6];
  const float* mem = (const float*)d_in[7];
  const float* z = (const float*)d_in[8];

  // workspace layout (fp32 elements): needs 134.5 MB
  float* ws = (float*)d_ws;
  float* Qb = ws;                  // 8388608  : Q -> sq -> (A of blend gemm)
  float* Kb = ws + 8388608;        // 8388608  : K -> sk
  float* Vb = ws + 16777216;       // 8388608  : V -> W = v - delta
  float* At = ws + 25165824;       // 8388608  : attn -> blend  ([b][h][s][e])
  float* dq = ws + 33554432;       // 32768    : sq . z per row
  float* dk = dq + 32768;          // 32768    : sk . z per row

  float* out = (float*)d_out;                       // 8192x1024
  float* outmem = out + (size_t)Msz * Dsz;          // 4x256x256
  float* outz = outmem + Hsz * HDsz * HDsz;         // 4x256

  hipMemsetAsync(outmem, 0, (size_t)(Hsz * HDsz * HDsz + Hsz * HDsz) * sizeof(float), stream);

  dim3 gg(8, 64);  // N/128, M/128
  gemm_nt<false><<<gg, 256, 0, stream>>>(Hs, Wq, nullptr, Qb);
  gemm_nt<false><<<gg, 256, 0, stream>>>(Hs, Wk, nullptr, Kb);
  gemm_nt<false><<<gg, 256, 0, stream>>>(Hs, Wv, nullptr, Vb);

  attn_kernel<<<dim3(128, 16), 256, 0, stream>>>(Qb, Kb, Vb, At);

  elu1_kernel<<<8192, 256, 0, stream>>>((float4*)Qb, (float4*)Kb);
  dens_kernel<<<8192, 256, 0, stream>>>(Qb, Kb, z, dq, dk);

  memread_gemm<<<dim3(2, 64, 4), 256, 0, stream>>>(Qb, mem, dq, betas, At, 0);  // blend
  memread_gemm<<<dim3(2, 64, 4), 256, 0, stream>>>(Kb, mem, dk, betas, Vb, 1);  // W

  mem_update<<<dim3(2, 2, 64), 256, 0, stream>>>(Kb, Vb, mem, outmem);
  z_update<<<64, 256, 0, stream>>>(Kb, z, outz);

  gemm_nt<true><<<gg, 256, 0, stream>>>(At, Wo, bo, out);
}

// Round 2
// 950.464 us; speedup vs baseline: 2.9182x; 2.9182x over previous
//
#include <hip/hip_runtime.h>

// Problem constants (B,S,D,H fixed by the reference)
#define Bsz 4
#define Ssz 2048
#define Dsz 1024
#define Hsz 4
#define HDsz 256
#define Msz 8192  // Bsz*Ssz

typedef unsigned short u16;
typedef __attribute__((ext_vector_type(8))) short bf16x8;  // 8 bf16 in 4 VGPRs
typedef __attribute__((ext_vector_type(4))) float f32x4;

__device__ __forceinline__ u16 f2b(float f) {  // fp32 -> bf16 RNE
  unsigned u = __float_as_uint(f);
  return (u16)((u + 0x7FFFu + ((u >> 16) & 1u)) >> 16);
}
__device__ __forceinline__ unsigned pk2(float a, float b) {
  return (unsigned)f2b(a) | ((unsigned)f2b(b) << 16);
}

// ---------------------------------------------------------------------------
// fp32 -> bf16 elementwise (for the 4 weight matrices; 1M elems each)
// ---------------------------------------------------------------------------
__global__ __launch_bounds__(256) void cvt_bf16(const float4* __restrict__ in,
                                                u16* __restrict__ outp) {
  size_t i = (size_t)blockIdx.x * 256 + threadIdx.x;
  float4 v = in[i];
  uint2 r; r.x = pk2(v.x, v.y); r.y = pk2(v.z, v.w);
  *(uint2*)(outp + i * 4) = r;
}

// ---------------------------------------------------------------------------
// bf16 MFMA GEMM: C[M,N] = A[M,K] * W[N,K]^T (+bias).  M=8192, N=K=1024.
// 128x128 tile, BK=32, 4 waves x (4x4 of 16x16x32 MFMA).
// AF32: A is fp32, converted to bf16 during staging. Writes fp32 C and/or
// bf16 C copy.  LDS stride 40 bf16 (80 B) keeps b128 frag reads ~2-way.
// ---------------------------------------------------------------------------
template <bool AF32>
__global__ __launch_bounds__(256) void gemm_mfma(const float* __restrict__ A32,
                                                 const u16* __restrict__ A16,
                                                 const u16* __restrict__ Wb,
                                                 const float* __restrict__ bias,
                                                 float* __restrict__ C32,
                                                 u16* __restrict__ Cbf) {
  __shared__ u16 sA[128 * 40];
  __shared__ u16 sB[128 * 40];
  const int tid = threadIdx.x;
  const int lane = tid & 63, quad = lane >> 4, l15 = lane & 15;
  const int w = tid >> 6;
  const int mw = (w >> 1) * 64, nw = (w & 1) * 64;
  const int m0 = blockIdx.y * 128, n0 = blockIdx.x * 128;
  const int srow = tid >> 1, sseg = (tid & 1) * 16;  // staging: 2 thr/row, 16 bf16 each
  f32x4 acc[4][4] = {};
  const u16* bp = Wb + (size_t)(n0 + srow) * Dsz + sseg;
  u16* sAw = &sA[srow * 40 + sseg];
  u16* sBw = &sB[srow * 40 + sseg];
  for (int k0 = 0; k0 < Dsz; k0 += 32) {
    __syncthreads();
    if (AF32) {
      const float* ap = A32 + (size_t)(m0 + srow) * Dsz + k0 + sseg;
      float4 f0 = *(const float4*)ap, f1 = *(const float4*)(ap + 4);
      float4 f2 = *(const float4*)(ap + 8), f3 = *(const float4*)(ap + 12);
      uint4 u0, u1;
      u0.x = pk2(f0.x, f0.y); u0.y = pk2(f0.z, f0.w);
      u0.z = pk2(f1.x, f1.y); u0.w = pk2(f1.z, f1.w);
      u1.x = pk2(f2.x, f2.y); u1.y = pk2(f2.z, f2.w);
      u1.z = pk2(f3.x, f3.y); u1.w = pk2(f3.z, f3.w);
      *(uint4*)sAw = u0; *(uint4*)(sAw + 8) = u1;
    } else {
      const u16* ap = A16 + (size_t)(m0 + srow) * Dsz + k0 + sseg;
      *(uint4*)sAw = *(const uint4*)ap;
      *(uint4*)(sAw + 8) = *(const uint4*)(ap + 8);
    }
    *(uint4*)sBw = *(const uint4*)(bp + k0);
    *(uint4*)(sBw + 8) = *(const uint4*)(bp + k0 + 8);
    __syncthreads();
    bf16x8 af[4], bfr[4];
#pragma unroll
    for (int i = 0; i < 4; ++i) {
      af[i] = *(const bf16x8*)&sA[(mw + i * 16 + l15) * 40 + quad * 8];
      bfr[i] = *(const bf16x8*)&sB[(nw + i * 16 + l15) * 40 + quad * 8];
    }
#pragma unroll
    for (int i = 0; i < 4; ++i)
#pragma unroll
      for (int j = 0; j < 4; ++j)
        acc[i][j] = __builtin_amdgcn_mfma_f32_16x16x32_bf16(af[i], bfr[j], acc[i][j], 0, 0, 0);
  }
  // epilogue: C row m = quad*4+r (C-layout row), col n = l15
#pragma unroll
  for (int j = 0; j < 4; ++j) {
    const int n = n0 + nw + j * 16 + l15;
    const float bv = bias ? bias[n] : 0.f;
#pragma unroll
    for (int i = 0; i < 4; ++i) {
#pragma unroll
      for (int r = 0; r < 4; ++r) {
        const int m = m0 + mw + i * 16 + quad * 4 + r;
        const float val = acc[i][j][r] + bv;
        const size_t idx = (size_t)m * Dsz + n;
        if (C32) C32[idx] = val;
        if (Cbf) Cbf[idx] = f2b(val);
      }
    }
  }
}

// ---------------------------------------------------------------------------
// V [b][s][h*256+e] fp32 -> V^T bf16 [bh][e][s]  (for PV B-operand k-contiguity)
// ---------------------------------------------------------------------------
__global__ __launch_bounds__(256) void transpose_v(const float* __restrict__ V,
                                                   u16* __restrict__ Vt) {
  __shared__ u16 tile[32 * 36];
  const int t = threadIdx.x;
  const int s0 = blockIdx.x * 32, e0 = blockIdx.y * 32, bh = blockIdx.z;
  const int b = bh >> 2, h = bh & 3;
  {
    const int s_l = t >> 3, e8 = (t & 7) * 4;
    float4 v = *(const float4*)(V + ((size_t)(b * Ssz) + s0 + s_l) * Dsz + h * HDsz + e0 + e8);
    uint2 r; r.x = pk2(v.x, v.y); r.y = pk2(v.z, v.w);
    *(uint2*)&tile[s_l * 36 + e8] = r;
  }
  __syncthreads();
  {
    const int e_l = t >> 3, s4 = (t & 7) * 4;
    u16 a = tile[(s4 + 0) * 36 + e_l], b2 = tile[(s4 + 1) * 36 + e_l];
    u16 c = tile[(s4 + 2) * 36 + e_l], d = tile[(s4 + 3) * 36 + e_l];
    uint2 r; r.x = (unsigned)a | ((unsigned)b2 << 16);
    r.y = (unsigned)c | ((unsigned)d << 16);
    *(uint2*)(Vt + ((size_t)bh * HDsz + e0 + e_l) * Ssz + s0 + s4) = r;
  }
}

// ---------------------------------------------------------------------------
// Flash attention, bf16 MFMA (16x16x32). Block = 4 waves x 16 Q rows = 64 q.
// Scores computed transposed (S^T = K*Q^T) so per-q softmax stats are
// per-lane (q = lane&15): reductions over lanes {l, l^16, l^32, l^48}.
// P^T (C-layout) -> P (A-layout) via xor16/xor32 butterfly.
// K tile [32][264] and V^T tile [256][40] in LDS. Output fp32 [bh][s][e].
// ---------------------------------------------------------------------------
__global__ __launch_bounds__(256) void attn_mfma(const u16* __restrict__ Qg,
                                                 const u16* __restrict__ Kg,
                                                 const u16* __restrict__ Vtg,
                                                 float* __restrict__ At) {
  const int gx = blockIdx.x;  // pair long+short q-tiles for load balance
  const int qt = (gx & 1) ? (31 - (gx >> 1)) : (gx >> 1);
  const int bh = blockIdx.y, b = bh >> 2, h = bh & 3;
  const int tid = threadIdx.x, w = tid >> 6, lane = tid & 63;
  const int quad = lane >> 4, l15 = lane & 15;
  __shared__ u16 sK[32 * 264];
  __shared__ u16 sV[256 * 40];
  const int q0w = qt * 64 + w * 16;
  // resident Q B-frags: n=q=l15, k=d=quad*8+j, 8 frags cover d=0..255
  bf16x8 qf[8];
  {
    const u16* qp = Qg + ((size_t)(b * Ssz) + q0w + l15) * Dsz + h * HDsz + quad * 8;
#pragma unroll
    for (int dd = 0; dd < 8; ++dd) qf[dd] = *(const bf16x8*)(qp + dd * 32);
  }
  f32x4 o[16] = {};  // O[q=quad*4+r][d=ds*16+l15]
  float m_old = -1e30f, l = 0.f;
  const int nkt = 2 * qt + 2;
  const int krow = tid >> 3, kseg = (tid & 7) * 32;
  const u16* kbase = Kg + ((size_t)(b * Ssz) + krow) * Dsz + h * HDsz + kseg;
  const u16* vbase = Vtg + ((size_t)bh * HDsz + tid) * Ssz;
  for (int kt = 0; kt < nkt; ++kt) {
    const int j0 = kt * 32;
    __syncthreads();
    {
      const u16* kp = kbase + (size_t)j0 * Dsz;
      u16* dkp = &sK[krow * 264 + kseg];
#pragma unroll
      for (int i = 0; i < 4; ++i) *(uint4*)(dkp + i * 8) = *(const uint4*)(kp + i * 8);
      const u16* vp = vbase + j0;
      u16* dvp = &sV[tid * 40];
#pragma unroll
      for (int i = 0; i < 4; ++i) *(uint4*)(dvp + i * 8) = *(const uint4*)(vp + i * 8);
    }
    __syncthreads();
    // QK^T transposed: S^T[key][q], A = K-frag (m=key=l15 [+16]), B = qf
    f32x4 s0v = {}, s1v = {};
#pragma unroll
    for (int dd = 0; dd < 8; ++dd) {
      bf16x8 a0 = *(const bf16x8*)&sK[l15 * 264 + dd * 32 + quad * 8];
      bf16x8 a1 = *(const bf16x8*)&sK[(16 + l15) * 264 + dd * 32 + quad * 8];
      s0v = __builtin_amdgcn_mfma_f32_16x16x32_bf16(a0, qf[dd], s0v, 0, 0, 0);
      s1v = __builtin_amdgcn_mfma_f32_16x16x32_bf16(a1, qf[dd], s1v, 0, 0, 0);
    }
    // causal mask: key row = quad*4+r (frag0) / +16 (frag1); col q = l15
    const int qg = q0w + l15;
    float p[8];
#pragma unroll
    for (int r = 0; r < 4; ++r) {
      const int kg = j0 + quad * 4 + r;
      p[r] = (kg <= qg) ? s0v[r] : -1e30f;
      p[4 + r] = (kg + 16 <= qg) ? s1v[r] : -1e30f;
    }
    // online softmax: stats per q = l15 across lanes {l, l^16, l^32, l^48}
    float mt = p[0];
#pragma unroll
    for (int i = 1; i < 8; ++i) mt = fmaxf(mt, p[i]);
    mt = fmaxf(mt, __shfl_xor(mt, 16));
    mt = fmaxf(mt, __shfl_xor(mt, 32));
    const float m_new = fmaxf(m_old, mt);
    const float alpha = __expf(m_old - m_new);
    float ts = 0.f;
#pragma unroll
    for (int i = 0; i < 8; ++i) { p[i] = __expf(p[i] - m_new); ts += p[i]; }
    ts += __shfl_xor(ts, 16);
    ts += __shfl_xor(ts, 32);
    l = l * alpha + ts;
    m_old = m_new;
    // rescale O (alpha indexed by q=quad*4+r, fetched via shfl)
    if (!__all(alpha == 1.0f)) {
      const float a0_ = __shfl(alpha, (lane & 48) | (quad * 4 + 0));
      const float a1_ = __shfl(alpha, (lane & 48) | (quad * 4 + 1));
      const float a2_ = __shfl(alpha, (lane & 48) | (quad * 4 + 2));
      const float a3_ = __shfl(alpha, (lane & 48) | (quad * 4 + 3));
#pragma unroll
      for (int ds = 0; ds < 16; ++ds) {
        o[ds][0] *= a0_; o[ds][1] *= a1_; o[ds][2] *= a2_; o[ds][3] *= a3_;
      }
    }
    // P^T (C-layout) -> P A-frag (m=q=l15, k=key=quad*8+j)
    float x[8];
#pragma unroll
    for (int i = 0; i < 8; ++i) x[i] = __shfl_xor(p[i], 16);
    const bool qe = (quad & 1) == 0;
    float Alo[8], Ahi[8];
#pragma unroll
    for (int i = 0; i < 4; ++i) {
      Alo[i] = qe ? p[i] : x[i];       // keys [ (quad>>1)*8 .. +8 )
      Alo[4 + i] = qe ? x[i] : p[i];
      Ahi[i] = qe ? p[4 + i] : x[4 + i];  // keys [16+(quad>>1)*8 .. +8)
      Ahi[4 + i] = qe ? x[4 + i] : p[4 + i];
    }
    float zz[8];
    const bool sendlo = (quad & 1) != 0;
#pragma unroll
    for (int i = 0; i < 8; ++i) zz[i] = __shfl_xor(sendlo ? Alo[i] : Ahi[i], 32);
    float fin[8];
#pragma unroll
    for (int i = 0; i < 8; ++i)
      fin[i] = (quad == 0) ? Alo[i] : (quad == 3) ? Ahi[i] : zz[i];
    uint4 pkv;
    pkv.x = pk2(fin[0], fin[1]); pkv.y = pk2(fin[2], fin[3]);
    pkv.z = pk2(fin[4], fin[5]); pkv.w = pk2(fin[6], fin[7]);
    bf16x8 pf = *(bf16x8*)&pkv;
    // PV: O[q][d] += P * V; B-frag = V^T[d=ds*16+l15][key=quad*8+j]
#pragma unroll
    for (int ds = 0; ds < 16; ++ds) {
      bf16x8 bv = *(const bf16x8*)&sV[(ds * 16 + l15) * 40 + quad * 8];
      o[ds] = __builtin_amdgcn_mfma_f32_16x16x32_bf16(pf, bv, o[ds], 0, 0, 0);
    }
  }
  float lr[4];
#pragma unroll
  for (int r = 0; r < 4; ++r) lr[r] = 1.f / __shfl(l, (lane & 48) | (quad * 4 + r));
  float* ob = At + ((size_t)bh * Ssz + q0w + quad * 4) * HDsz + l15;
#pragma unroll
  for (int r = 0; r < 4; ++r)
#pragma unroll
    for (int ds = 0; ds < 16; ++ds)
      ob[(size_t)r * HDsz + ds * 16] = o[ds][r] * lr[r];
}

// ---------------------------------------------------------------------------
// sq = elu(q)+1, in-place on fp32 Q and K buffers.
// ---------------------------------------------------------------------------
__global__ __launch_bounds__(256) void elu1_kernel(float4* __restrict__ Q4,
                                                   float4* __restrict__ K4) {
  size_t i = (size_t)blockIdx.x * 256 + threadIdx.x;
  float4 q = Q4[i];
  q.x = q.x > 0.f ? q.x + 1.f : __expf(q.x);
  q.y = q.y > 0.f ? q.y + 1.f : __expf(q.y);
  q.z = q.z > 0.f ? q.z + 1.f : __expf(q.z);
  q.w = q.w > 0.f ? q.w + 1.f : __expf(q.w);
  Q4[i] = q;
  float4 k = K4[i];
  k.x = k.x > 0.f ? k.x + 1.f : __expf(k.x);
  k.y = k.y > 0.f ? k.y + 1.f : __expf(k.y);
  k.z = k.z > 0.f ? k.z + 1.f : __expf(k.z);
  k.w = k.w > 0.f ? k.w + 1.f : __expf(k.w);
  K4[i] = k;
}

// ---------------------------------------------------------------------------
// denq[r] = sq_row . z[h],  denk[r] = sk_row . z[h]
// ---------------------------------------------------------------------------
__global__ __launch_bounds__(256) void dens_kernel(const float* __restrict__ SQ,
                                                   const float* __restrict__ SK,
                                                   const float* __restrict__ z,
                                                   float* __restrict__ denq,
                                                   float* __restrict__ denk) {
  const int wid = threadIdx.x >> 6, lane = threadIdx.x & 63;
  const int r = blockIdx.x * 4 + wid;
  const int b = r >> 13, h = (r >> 11) & 3, s = r & 2047;
  const size_t base = ((size_t)(b * Ssz + s)) * Dsz + h * HDsz + lane * 4;
  float4 zq = *(const float4*)(z + h * HDsz + lane * 4);
  float4 q4 = *(const float4*)(SQ + base);
  float4 k4 = *(const float4*)(SK + base);
  float pq = q4.x * zq.x + q4.y * zq.y + q4.z * zq.z + q4.w * zq.w;
  float pk = k4.x * zq.x + k4.y * zq.y + k4.z * zq.z + k4.w * zq.w;
#pragma unroll
  for (int off = 32; off; off >>= 1) {
    pq += __shfl_down(pq, off);
    pk += __shfl_down(pk, off);
  }
  if (lane == 0) { denq[r] = pq; denk[r] = pk; }
}

// ---------------------------------------------------------------------------
// Per-head NN GEMM acc[m,e] = sum_d Asrc[m,h*256+d]*mem[h][d][e], fp32.
// mode 0: blend = g*acc/den + (1-g)*attn  -> written as bf16 row-major [m][1024]
// mode 1: io(V) = v - acc/den (fp32 in place)
// ---------------------------------------------------------------------------
__global__ __launch_bounds__(256) void memread_gemm(const float* __restrict__ Asrc,
                                                    const float* __restrict__ mem,
                                                    const float* __restrict__ dens,
                                                    const float* __restrict__ betas,
                                                    float* __restrict__ io,
                                                    u16* __restrict__ bfout, int mode) {
  const int h = blockIdx.z;
  const int tid = threadIdx.x, tx = tid & 15, ty = tid >> 4;
  const int m0 = blockIdx.y * 128, n0 = blockIdx.x * 128;
  __shared__ float As[16][132];
  __shared__ float Bs[16][132];
  float acc[8][8] = {};
  for (int k0 = 0; k0 < HDsz; k0 += 16) {
#pragma unroll
    for (int i = 0; i < 2; ++i) {
      int f4 = i * 256 + tid;
      {
        int row = f4 >> 2, c4 = f4 & 3;
        float4 v = *(const float4*)(Asrc + (size_t)(m0 + row) * Dsz + h * HDsz + k0 + c4 * 4);
        As[c4 * 4 + 0][row] = v.x; As[c4 * 4 + 1][row] = v.y;
        As[c4 * 4 + 2][row] = v.z; As[c4 * 4 + 3][row] = v.w;
      }
      {
        int k = f4 >> 5, e4 = f4 & 31;
        float4 v = *(const float4*)(mem + (size_t)h * 65536 + (size_t)(k0 + k) * HDsz + n0 + e4 * 4);
        *(float4*)(&Bs[k][e4 * 4]) = v;
      }
    }
    __syncthreads();
#pragma unroll
    for (int k = 0; k < 16; ++k) {
      float a[8], b[8];
      *(float4*)(a) = *(const float4*)(&As[k][ty * 8]);
      *(float4*)(a + 4) = *(const float4*)(&As[k][ty * 8 + 4]);
      *(float4*)(b) = *(const float4*)(&Bs[k][tx * 8]);
      *(float4*)(b + 4) = *(const float4*)(&Bs[k][tx * 8 + 4]);
#pragma unroll
      for (int i = 0; i < 8; ++i)
#pragma unroll
        for (int j = 0; j < 8; ++j) acc[i][j] = fmaf(a[i], b[j], acc[i][j]);
    }
    __syncthreads();
  }
  const float g = 1.f / (1.f + __expf(-betas[h]));
#pragma unroll
  for (int i = 0; i < 8; ++i) {
    int m = m0 + ty * 8 + i;
    int b = m >> 11, s = m & 2047;
    int rowidx = ((b << 2) + h) * Ssz + s;
    float inv = 1.f / (dens[rowidx] + 1e-6f);
    if (mode == 0) {
      const float* p = io + (size_t)rowidx * HDsz + n0 + tx * 8;
      float4 a0 = *(const float4*)p, a1 = *(const float4*)(p + 4);
      float o0x = g * acc[i][0] * inv + (1.f - g) * a0.x;
      float o0y = g * acc[i][1] * inv + (1.f - g) * a0.y;
      float o0z = g * acc[i][2] * inv + (1.f - g) * a0.z;
      float o0w = g * acc[i][3] * inv + (1.f - g) * a0.w;
      float o1x = g * acc[i][4] * inv + (1.f - g) * a1.x;
      float o1y = g * acc[i][5] * inv + (1.f - g) * a1.y;
      float o1z = g * acc[i][6] * inv + (1.f - g) * a1.z;
      float o1w = g * acc[i][7] * inv + (1.f - g) * a1.w;
      u16* bp2 = bfout + (size_t)m * Dsz + h * HDsz + n0 + tx * 8;
      uint4 pk;
      pk.x = pk2(o0x, o0y); pk.y = pk2(o0z, o0w);
      pk.z = pk2(o1x, o1y); pk.w = pk2(o1z, o1w);
      *(uint4*)bp2 = pk;
    } else {
      float* p = io + (size_t)m * Dsz + h * HDsz + n0 + tx * 8;
      float4 v0 = *(float4*)p, v1 = *(float4*)(p + 4);
      float4 o0, o1;
      o0.x = v0.x - acc[i][0] * inv; o0.y = v0.y - acc[i][1] * inv;
      o0.z = v0.z - acc[i][2] * inv; o0.w = v0.w - acc[i][3] * inv;
      o1.x = v1.x - acc[i][4] * inv; o1.y = v1.y - acc[i][5] * inv;
      o1.z = v1.z - acc[i][6] * inv; o1.w = v1.w - acc[i][7] * inv;
      *(float4*)p = o0;
      *(float4*)(p + 4) = o1;
    }
  }
}

// ---------------------------------------------------------------------------
// mem_new[h][d][e] = mem + (1/B) sum_m sk[m,h*256+d] * W[m,h*256+e]
// split-K 16 x 512 rows, atomicAdd into zeroed output.
// ---------------------------------------------------------------------------
__global__ __launch_bounds__(256) void mem_update(const float* __restrict__ SK,
                                                  const float* __restrict__ W,
                                                  const float* __restrict__ mem,
                                                  float* __restrict__ outmem) {
  const int h = blockIdx.z >> 4, chunk = blockIdx.z & 15;
  const int d0 = blockIdx.y * 128, e0 = blockIdx.x * 128;
  const int m0 = chunk * 512;
  const int tid = threadIdx.x, tx = tid & 15, ty = tid >> 4;
  __shared__ float As[16][132];
  __shared__ float Bs[16][132];
  float acc[8][8] = {};
  for (int mt = 0; mt < 512; mt += 16) {
#pragma unroll
    for (int i = 0; i < 2; ++i) {
      int f4 = i * 256 + tid;
      int mi = f4 >> 5, c4 = f4 & 31;
      size_t rb = (size_t)(m0 + mt + mi) * Dsz + h * HDsz;
      *(float4*)(&As[mi][c4 * 4]) = *(const float4*)(SK + rb + d0 + c4 * 4);
      *(float4*)(&Bs[mi][c4 * 4]) = *(const float4*)(W + rb + e0 + c4 * 4);
    }
    __syncthreads();
#pragma unroll
    for (int k = 0; k < 16; ++k) {
      float a[8], b[8];
      *(float4*)(a) = *(const float4*)(&As[k][ty * 8]);
      *(float4*)(a + 4) = *(const float4*)(&As[k][ty * 8 + 4]);
      *(float4*)(b) = *(const float4*)(&Bs[k][tx * 8]);
      *(float4*)(b + 4) = *(const float4*)(&Bs[k][tx * 8 + 4]);
#pragma unroll
      for (int i = 0; i < 8; ++i)
#pragma unroll
        for (int j = 0; j < 8; ++j) acc[i][j] = fmaf(a[i], b[j], acc[i][j]);
    }
    __syncthreads();
  }
#pragma unroll
  for (int i = 0; i < 8; ++i) {
    int d = d0 + ty * 8 + i;
#pragma unroll
    for (int j = 0; j < 8; ++j) {
      int e = e0 + tx * 8 + j;
      float val = acc[i][j] * 0.25f;
      size_t idx = (size_t)h * 65536 + (size_t)d * HDsz + e;
      if (chunk == 0) val += mem[idx];
      atomicAdd(outmem + idx, val);
    }
  }
}

// ---------------------------------------------------------------------------
// z_new[h][d] = z[h][d] + (1/B) sum_{b,s} sk[b,h,s,d]
// ---------------------------------------------------------------------------
__global__ __launch_bounds__(256) void z_update(const float* __restrict__ SK,
                                                const float* __restrict__ z_in,
                                                float* __restrict__ z_out) {
  const int h = blockIdx.x >> 4, chunk = blockIdx.x & 15;
  const int t = threadIdx.x;
  const int m0 = chunk * 512;
  float sum = 0.f;
  for (int i = 0; i < 512; ++i) sum += SK[(size_t)(m0 + i) * Dsz + h * HDsz + t];
  float val = sum * 0.25f;
  if (chunk == 0) val += z_in[h * HDsz + t];
  atomicAdd(z_out + h * HDsz + t, val);
}

// ---------------------------------------------------------------------------
extern "C" void kernel_launch(void* const* d_in, const int* in_sizes, int n_in,
                              void* d_out, int out_size, void* d_ws, size_t ws_size,
                              hipStream_t stream) {
  (void)in_sizes; (void)n_in; (void)out_size; (void)ws_size;
  const float* Hs = (const float*)d_in[0];
  const float* Wq = (const float*)d_in[1];
  const float* Wk = (const float*)d_in[2];
  const float* Wv = (const float*)d_in[3];
  const float* Wo = (const float*)d_in[4];
  const float* bo = (const float*)d_in[5];
  const float* betas = (const float*)d_in[6];
  const float* mem = (const float*)d_in[7];
  const float* z = (const float*)d_in[8];

  // fp32 workspace region (134.5 MB)
  float* ws = (float*)d_ws;
  float* Qb = ws;                   // 8388608 : Q fp32 -> sq
  float* Kb = ws + 8388608;         // K fp32 -> sk
  float* Vb = ws + 16777216;        // V fp32 -> W = v - delta
  float* At = ws + 25165824;        // attn out fp32 [bh][s][e]
  float* dq = ws + 33554432;        // 32768
  float* dk = ws + 33554432 + 32768;
  // bf16 region (58.7 MB)
  u16* ub = (u16*)(ws + 33554432 + 65536);
  u16* Wqb = ub;                    // 4 x 1048576 weight copies
  u16* Wkb = ub + 1048576;
  u16* Wvb = ub + 2097152;
  u16* Wob = ub + 3145728;
  u16* Qbf = ub + 4194304;          // 8388608 : bf16 Q; later reused as bf16 blend
  u16* Kbf = ub + 4194304 + 8388608;
  u16* Vt = ub + 4194304 + 16777216;  // V^T bf16 [bh][e][s]

  float* out = (float*)d_out;                 // 8192x1024
  float* outmem = out + (size_t)Msz * Dsz;    // 4x256x256
  float* outz = outmem + Hsz * HDsz * HDsz;   // 4x256

  hipMemsetAsync(outmem, 0, (size_t)(Hsz * HDsz * HDsz + Hsz * HDsz) * sizeof(float), stream);

  cvt_bf16<<<1024, 256, 0, stream>>>((const float4*)Wq, Wqb);
  cvt_bf16<<<1024, 256, 0, stream>>>((const float4*)Wk, Wkb);
  cvt_bf16<<<1024, 256, 0, stream>>>((const float4*)Wv, Wvb);
  cvt_bf16<<<1024, 256, 0, stream>>>((const float4*)Wo, Wob);

  dim3 gg(8, 64);  // N/128, M/128
  gemm_mfma<true><<<gg, 256, 0, stream>>>(Hs, nullptr, Wqb, nullptr, Qb, Qbf);
  gemm_mfma<true><<<gg, 256, 0, stream>>>(Hs, nullptr, Wkb, nullptr, Kb, Kbf);
  gemm_mfma<true><<<gg, 256, 0, stream>>>(Hs, nullptr, Wvb, nullptr, Vb, nullptr);

  transpose_v<<<dim3(64, 8, 16), 256, 0, stream>>>(Vb, Vt);
  attn_mfma<<<dim3(32, 16), 256, 0, stream>>>(Qbf, Kbf, Vt, At);

  elu1_kernel<<<8192, 256, 0, stream>>>((float4*)Qb, (float4*)Kb);
  dens_kernel<<<8192, 256, 0, stream>>>(Qb, Kb, z, dq, dk);

  // blend -> bf16 row-major into Qbf (Q bf16 is dead after attn)
  memread_gemm<<<dim3(2, 64, 4), 256, 0, stream>>>(Qb, mem, dq, betas, At, Qbf, 0);
  memread_gemm<<<dim3(2, 64, 4), 256, 0, stream>>>(Kb, mem, dk, betas, Vb, nullptr, 1);

  mem_update<<<dim3(2, 2, 64), 256, 0, stream>>>(Kb, Vb, mem, outmem);
  z_update<<<64, 256, 0, stream>>>(Kb, z, outz);

  gemm_mfma<false><<<gg, 256, 0, stream>>>(nullptr, Qbf, Wob, bo, out, nullptr);
}

// Round 3
// 655.047 us; speedup vs baseline: 4.2343x; 1.4510x over previous
//
#include <hip/hip_runtime.h>

// Problem constants (B,S,D,H fixed by the reference)
#define Bsz 4
#define Ssz 2048
#define Dsz 1024
#define Hsz 4
#define HDsz 256
#define Msz 8192  // Bsz*Ssz

typedef unsigned short u16;
typedef __attribute__((ext_vector_type(8))) short bf16x8;  // 8 bf16 in 4 VGPRs
typedef __attribute__((ext_vector_type(4))) float f32x4;

__device__ __forceinline__ u16 f2b(float f) {  // fp32 -> bf16 RNE
  unsigned u = __float_as_uint(f);
  return (u16)((u + 0x7FFFu + ((u >> 16) & 1u)) >> 16);
}
__device__ __forceinline__ unsigned pk2(float a, float b) {
  return (unsigned)f2b(a) | ((unsigned)f2b(b) << 16);
}

// ---------------------------------------------------------------------------
// fp32 -> bf16 elementwise (for the 4 weight matrices; 1M elems each)
// ---------------------------------------------------------------------------
__global__ __launch_bounds__(256) void cvt_bf16(const float4* __restrict__ in,
                                                u16* __restrict__ outp) {
  size_t i = (size_t)blockIdx.x * 256 + threadIdx.x;
  float4 v = in[i];
  uint2 r; r.x = pk2(v.x, v.y); r.y = pk2(v.z, v.w);
  *(uint2*)(outp + i * 4) = r;
}

// ---------------------------------------------------------------------------
// bf16 MFMA GEMM: C[M,N] = A[M,K] * W[N,K]^T (+bias).  M=8192, N=K=1024.
// 128x128 tile, BK=32, 4 waves x (4x4 of 16x16x32 MFMA).
// ---------------------------------------------------------------------------
template <bool AF32>
__global__ __launch_bounds__(256) void gemm_mfma(const float* __restrict__ A32,
                                                 const u16* __restrict__ A16,
                                                 const u16* __restrict__ Wb,
                                                 const float* __restrict__ bias,
                                                 float* __restrict__ C32,
                                                 u16* __restrict__ Cbf) {
  __shared__ u16 sA[128 * 40];
  __shared__ u16 sB[128 * 40];
  const int tid = threadIdx.x;
  const int lane = tid & 63, quad = lane >> 4, l15 = lane & 15;
  const int w = tid >> 6;
  const int mw = (w >> 1) * 64, nw = (w & 1) * 64;
  const int m0 = blockIdx.y * 128, n0 = blockIdx.x * 128;
  const int srow = tid >> 1, sseg = (tid & 1) * 16;  // staging: 2 thr/row, 16 bf16 each
  f32x4 acc[4][4] = {};
  const u16* bp = Wb + (size_t)(n0 + srow) * Dsz + sseg;
  u16* sAw = &sA[srow * 40 + sseg];
  u16* sBw = &sB[srow * 40 + sseg];
  for (int k0 = 0; k0 < Dsz; k0 += 32) {
    __syncthreads();
    if (AF32) {
      const float* ap = A32 + (size_t)(m0 + srow) * Dsz + k0 + sseg;
      float4 f0 = *(const float4*)ap, f1 = *(const float4*)(ap + 4);
      float4 f2 = *(const float4*)(ap + 8), f3 = *(const float4*)(ap + 12);
      uint4 u0, u1;
      u0.x = pk2(f0.x, f0.y); u0.y = pk2(f0.z, f0.w);
      u0.z = pk2(f1.x, f1.y); u0.w = pk2(f1.z, f1.w);
      u1.x = pk2(f2.x, f2.y); u1.y = pk2(f2.z, f2.w);
      u1.z = pk2(f3.x, f3.y); u1.w = pk2(f3.z, f3.w);
      *(uint4*)sAw = u0; *(uint4*)(sAw + 8) = u1;
    } else {
      const u16* ap = A16 + (size_t)(m0 + srow) * Dsz + k0 + sseg;
      *(uint4*)sAw = *(const uint4*)ap;
      *(uint4*)(sAw + 8) = *(const uint4*)(ap + 8);
    }
    *(uint4*)sBw = *(const uint4*)(bp + k0);
    *(uint4*)(sBw + 8) = *(const uint4*)(bp + k0 + 8);
    __syncthreads();
    bf16x8 af[4], bfr[4];
#pragma unroll
    for (int i = 0; i < 4; ++i) {
      af[i] = *(const bf16x8*)&sA[(mw + i * 16 + l15) * 40 + quad * 8];
      bfr[i] = *(const bf16x8*)&sB[(nw + i * 16 + l15) * 40 + quad * 8];
    }
#pragma unroll
    for (int i = 0; i < 4; ++i)
#pragma unroll
      for (int j = 0; j < 4; ++j)
        acc[i][j] = __builtin_amdgcn_mfma_f32_16x16x32_bf16(af[i], bfr[j], acc[i][j], 0, 0, 0);
  }
#pragma unroll
  for (int j = 0; j < 4; ++j) {
    const int n = n0 + nw + j * 16 + l15;
    const float bv = bias ? bias[n] : 0.f;
#pragma unroll
    for (int i = 0; i < 4; ++i) {
#pragma unroll
      for (int r = 0; r < 4; ++r) {
        const int m = m0 + mw + i * 16 + quad * 4 + r;
        const float val = acc[i][j][r] + bv;
        const size_t idx = (size_t)m * Dsz + n;
        if (C32) C32[idx] = val;
        if (Cbf) Cbf[idx] = f2b(val);
      }
    }
  }
}

// ---------------------------------------------------------------------------
// V [b][s][h*256+e] fp32 -> V^T bf16 [bh][e][s]
// ---------------------------------------------------------------------------
__global__ __launch_bounds__(256) void transpose_v(const float* __restrict__ V,
                                                   u16* __restrict__ Vt) {
  __shared__ u16 tile[32 * 36];
  const int t = threadIdx.x;
  const int s0 = blockIdx.x * 32, e0 = blockIdx.y * 32, bh = blockIdx.z;
  const int b = bh >> 2, h = bh & 3;
  {
    const int s_l = t >> 3, e8 = (t & 7) * 4;
    float4 v = *(const float4*)(V + ((size_t)(b * Ssz) + s0 + s_l) * Dsz + h * HDsz + e0 + e8);
    uint2 r; r.x = pk2(v.x, v.y); r.y = pk2(v.z, v.w);
    *(uint2*)&tile[s_l * 36 + e8] = r;
  }
  __syncthreads();
  {
    const int e_l = t >> 3, s4 = (t & 7) * 4;
    u16 a = tile[(s4 + 0) * 36 + e_l], b2 = tile[(s4 + 1) * 36 + e_l];
    u16 c = tile[(s4 + 2) * 36 + e_l], d = tile[(s4 + 3) * 36 + e_l];
    uint2 r; r.x = (unsigned)a | ((unsigned)b2 << 16);
    r.y = (unsigned)c | ((unsigned)d << 16);
    *(uint2*)(Vt + ((size_t)bh * HDsz + e0 + e_l) * Ssz + s0 + s4) = r;
  }
}

// ---------------------------------------------------------------------------
// Flash attention, bf16 MFMA (16x16x32). Block = 4 waves x 16 Q rows = 64 q.
// ---------------------------------------------------------------------------
__global__ __launch_bounds__(256) void attn_mfma(const u16* __restrict__ Qg,
                                                 const u16* __restrict__ Kg,
                                                 const u16* __restrict__ Vtg,
                                                 float* __restrict__ At) {
  const int gx = blockIdx.x;  // pair long+short q-tiles for load balance
  const int qt = (gx & 1) ? (31 - (gx >> 1)) : (gx >> 1);
  const int bh = blockIdx.y, b = bh >> 2, h = bh & 3;
  const int tid = threadIdx.x, w = tid >> 6, lane = tid & 63;
  const int quad = lane >> 4, l15 = lane & 15;
  __shared__ u16 sK[32 * 264];
  __shared__ u16 sV[256 * 40];
  const int q0w = qt * 64 + w * 16;
  bf16x8 qf[8];
  {
    const u16* qp = Qg + ((size_t)(b * Ssz) + q0w + l15) * Dsz + h * HDsz + quad * 8;
#pragma unroll
    for (int dd = 0; dd < 8; ++dd) qf[dd] = *(const bf16x8*)(qp + dd * 32);
  }
  f32x4 o[16] = {};
  float m_old = -1e30f, l = 0.f;
  const int nkt = 2 * qt + 2;
  const int krow = tid >> 3, kseg = (tid & 7) * 32;
  const u16* kbase = Kg + ((size_t)(b * Ssz) + krow) * Dsz + h * HDsz + kseg;
  const u16* vbase = Vtg + ((size_t)bh * HDsz + tid) * Ssz;
  for (int kt = 0; kt < nkt; ++kt) {
    const int j0 = kt * 32;
    __syncthreads();
    {
      const u16* kp = kbase + (size_t)j0 * Dsz;
      u16* dkp = &sK[krow * 264 + kseg];
#pragma unroll
      for (int i = 0; i < 4; ++i) *(uint4*)(dkp + i * 8) = *(const uint4*)(kp + i * 8);
      const u16* vp = vbase + j0;
      u16* dvp = &sV[tid * 40];
#pragma unroll
      for (int i = 0; i < 4; ++i) *(uint4*)(dvp + i * 8) = *(const uint4*)(vp + i * 8);
    }
    __syncthreads();
    f32x4 s0v = {}, s1v = {};
#pragma unroll
    for (int dd = 0; dd < 8; ++dd) {
      bf16x8 a0 = *(const bf16x8*)&sK[l15 * 264 + dd * 32 + quad * 8];
      bf16x8 a1 = *(const bf16x8*)&sK[(16 + l15) * 264 + dd * 32 + quad * 8];
      s0v = __builtin_amdgcn_mfma_f32_16x16x32_bf16(a0, qf[dd], s0v, 0, 0, 0);
      s1v = __builtin_amdgcn_mfma_f32_16x16x32_bf16(a1, qf[dd], s1v, 0, 0, 0);
    }
    const int qg = q0w + l15;
    float p[8];
#pragma unroll
    for (int r = 0; r < 4; ++r) {
      const int kg = j0 + quad * 4 + r;
      p[r] = (kg <= qg) ? s0v[r] : -1e30f;
      p[4 + r] = (kg + 16 <= qg) ? s1v[r] : -1e30f;
    }
    float mt = p[0];
#pragma unroll
    for (int i = 1; i < 8; ++i) mt = fmaxf(mt, p[i]);
    mt = fmaxf(mt, __shfl_xor(mt, 16));
    mt = fmaxf(mt, __shfl_xor(mt, 32));
    const float m_new = fmaxf(m_old, mt);
    const float alpha = __expf(m_old - m_new);
    float ts = 0.f;
#pragma unroll
    for (int i = 0; i < 8; ++i) { p[i] = __expf(p[i] - m_new); ts += p[i]; }
    ts += __shfl_xor(ts, 16);
    ts += __shfl_xor(ts, 32);
    l = l * alpha + ts;
    m_old = m_new;
    if (!__all(alpha == 1.0f)) {
      const float a0_ = __shfl(alpha, (lane & 48) | (quad * 4 + 0));
      const float a1_ = __shfl(alpha, (lane & 48) | (quad * 4 + 1));
      const float a2_ = __shfl(alpha, (lane & 48) | (quad * 4 + 2));
      const float a3_ = __shfl(alpha, (lane & 48) | (quad * 4 + 3));
#pragma unroll
      for (int ds = 0; ds < 16; ++ds) {
        o[ds][0] *= a0_; o[ds][1] *= a1_; o[ds][2] *= a2_; o[ds][3] *= a3_;
      }
    }
    float x[8];
#pragma unroll
    for (int i = 0; i < 8; ++i) x[i] = __shfl_xor(p[i], 16);
    const bool qe = (quad & 1) == 0;
    float Alo[8], Ahi[8];
#pragma unroll
    for (int i = 0; i < 4; ++i) {
      Alo[i] = qe ? p[i] : x[i];
      Alo[4 + i] = qe ? x[i] : p[i];
      Ahi[i] = qe ? p[4 + i] : x[4 + i];
      Ahi[4 + i] = qe ? x[4 + i] : p[4 + i];
    }
    float zz[8];
    const bool sendlo = (quad & 1) != 0;
#pragma unroll
    for (int i = 0; i < 8; ++i) zz[i] = __shfl_xor(sendlo ? Alo[i] : Ahi[i], 32);
    float fin[8];
#pragma unroll
    for (int i = 0; i < 8; ++i)
      fin[i] = (quad == 0) ? Alo[i] : (quad == 3) ? Ahi[i] : zz[i];
    uint4 pkv;
    pkv.x = pk2(fin[0], fin[1]); pkv.y = pk2(fin[2], fin[3]);
    pkv.z = pk2(fin[4], fin[5]); pkv.w = pk2(fin[6], fin[7]);
    bf16x8 pf = *(bf16x8*)&pkv;
#pragma unroll
    for (int ds = 0; ds < 16; ++ds) {
      bf16x8 bv = *(const bf16x8*)&sV[(ds * 16 + l15) * 40 + quad * 8];
      o[ds] = __builtin_amdgcn_mfma_f32_16x16x32_bf16(pf, bv, o[ds], 0, 0, 0);
    }
  }
  float lr[4];
#pragma unroll
  for (int r = 0; r < 4; ++r) lr[r] = 1.f / __shfl(l, (lane & 48) | (quad * 4 + r));
  float* ob = At + ((size_t)bh * Ssz + q0w + quad * 4) * HDsz + l15;
#pragma unroll
  for (int r = 0; r < 4; ++r)
#pragma unroll
    for (int ds = 0; ds < 16; ++ds)
      ob[(size_t)r * HDsz + ds * 16] = o[ds][r] * lr[r];
}

// ---------------------------------------------------------------------------
// sq = elu(q)+1, in-place on fp32 Q and K buffers.
// ---------------------------------------------------------------------------
__global__ __launch_bounds__(256) void elu1_kernel(float4* __restrict__ Q4,
                                                   float4* __restrict__ K4) {
  size_t i = (size_t)blockIdx.x * 256 + threadIdx.x;
  float4 q = Q4[i];
  q.x = q.x > 0.f ? q.x + 1.f : __expf(q.x);
  q.y = q.y > 0.f ? q.y + 1.f : __expf(q.y);
  q.z = q.z > 0.f ? q.z + 1.f : __expf(q.z);
  q.w = q.w > 0.f ? q.w + 1.f : __expf(q.w);
  Q4[i] = q;
  float4 k = K4[i];
  k.x = k.x > 0.f ? k.x + 1.f : __expf(k.x);
  k.y = k.y > 0.f ? k.y + 1.f : __expf(k.y);
  k.z = k.z > 0.f ? k.z + 1.f : __expf(k.z);
  k.w = k.w > 0.f ? k.w + 1.f : __expf(k.w);
  K4[i] = k;
}

// ---------------------------------------------------------------------------
// denq[r] = sq_row . z[h],  denk[r] = sk_row . z[h]
// ---------------------------------------------------------------------------
__global__ __launch_bounds__(256) void dens_kernel(const float* __restrict__ SQ,
                                                   const float* __restrict__ SK,
                                                   const float* __restrict__ z,
                                                   float* __restrict__ denq,
                                                   float* __restrict__ denk) {
  const int wid = threadIdx.x >> 6, lane = threadIdx.x & 63;
  const int r = blockIdx.x * 4 + wid;
  const int b = r >> 13, h = (r >> 11) & 3, s = r & 2047;
  const size_t base = ((size_t)(b * Ssz + s)) * Dsz + h * HDsz + lane * 4;
  float4 zq = *(const float4*)(z + h * HDsz + lane * 4);
  float4 q4 = *(const float4*)(SQ + base);
  float4 k4 = *(const float4*)(SK + base);
  float pq = q4.x * zq.x + q4.y * zq.y + q4.z * zq.z + q4.w * zq.w;
  float pk = k4.x * zq.x + k4.y * zq.y + k4.z * zq.z + k4.w * zq.w;
#pragma unroll
  for (int off = 32; off; off >>= 1) {
    pq += __shfl_down(pq, off);
    pk += __shfl_down(pk, off);
  }
  if (lane == 0) { denq[r] = pq; denk[r] = pk; }
}

// ---------------------------------------------------------------------------
// Per-head MFMA GEMM: acc[m,e] = sum_d Asrc[m,h*256+d] * mem[h][d][e].
// A staged fp32->bf16 row-major; B (mem) staged transposed [e][d] in LDS.
// mode 0: blend = g*acc/den + (1-g)*At -> bf16 row-major [m][1024] (bfout)
// mode 1: Vio = v - acc/den (fp32 in place)
// grid (2 e-tiles, 64 m-tiles, 4 heads), 256 threads.
// ---------------------------------------------------------------------------
__global__ __launch_bounds__(256) void memread_mfma(const float* __restrict__ Asrc,
                                                    const float* __restrict__ mem,
                                                    const float* __restrict__ dens,
                                                    const float* __restrict__ betas,
                                                    const float* __restrict__ At,
                                                    float* __restrict__ Vio,
                                                    u16* __restrict__ bfout, int mode) {
  const int h = blockIdx.z;
  const int tid = threadIdx.x, lane = tid & 63, w = tid >> 6;
  const int quad = lane >> 4, l15 = lane & 15;
  const int mw = (w >> 1) * 64, ew = (w & 1) * 64;
  const int m0 = blockIdx.y * 128, e0t = blockIdx.x * 128;
  __shared__ u16 sA[128 * 40];  // [m][k]
  __shared__ u16 sB[128 * 40];  // [e][k]
  const int srow = tid >> 1, sseg = (tid & 1) * 16;
  const int k4 = (tid & 7) * 4, e4 = (tid >> 3) * 4;
  f32x4 acc[4][4] = {};
  for (int k0 = 0; k0 < HDsz; k0 += 32) {
    __syncthreads();
    {  // A row-major, convert
      const float* ap = Asrc + (size_t)(m0 + srow) * Dsz + h * HDsz + k0 + sseg;
      float4 f0 = *(const float4*)ap, f1 = *(const float4*)(ap + 4);
      float4 f2 = *(const float4*)(ap + 8), f3 = *(const float4*)(ap + 12);
      uint4 u0, u1;
      u0.x = pk2(f0.x, f0.y); u0.y = pk2(f0.z, f0.w);
      u0.z = pk2(f1.x, f1.y); u0.w = pk2(f1.z, f1.w);
      u1.x = pk2(f2.x, f2.y); u1.y = pk2(f2.z, f2.w);
      u1.z = pk2(f3.x, f3.y); u1.w = pk2(f3.z, f3.w);
      u16* dst = &sA[srow * 40 + sseg];
      *(uint4*)dst = u0; *(uint4*)(dst + 8) = u1;
    }
    {  // B transpose: mem[d=k0+k4+i][e0t+e4+c] -> sB[e][k]
      const float* bp = mem + (size_t)h * 65536 + (size_t)(k0 + k4) * HDsz + e0t + e4;
      float4 r0 = *(const float4*)bp;
      float4 r1 = *(const float4*)(bp + HDsz);
      float4 r2 = *(const float4*)(bp + 2 * HDsz);
      float4 r3 = *(const float4*)(bp + 3 * HDsz);
      const float* rr[4] = {(const float*)&r0, (const float*)&r1,
                            (const float*)&r2, (const float*)&r3};
#pragma unroll
      for (int c = 0; c < 4; ++c) {
        uint2 u;
        u.x = pk2(rr[0][c], rr[1][c]);
        u.y = pk2(rr[2][c], rr[3][c]);
        *(uint2*)&sB[(e4 + c) * 40 + k4] = u;
      }
    }
    __syncthreads();
    bf16x8 af[4], bfr[4];
#pragma unroll
    for (int i = 0; i < 4; ++i) {
      af[i] = *(const bf16x8*)&sA[(mw + i * 16 + l15) * 40 + quad * 8];
      bfr[i] = *(const bf16x8*)&sB[(ew + i * 16 + l15) * 40 + quad * 8];
    }
#pragma unroll
    for (int i = 0; i < 4; ++i)
#pragma unroll
      for (int j = 0; j < 4; ++j)
        acc[i][j] = __builtin_amdgcn_mfma_f32_16x16x32_bf16(af[i], bfr[j], acc[i][j], 0, 0, 0);
  }
  const float g = 1.f / (1.f + __expf(-betas[h]));
#pragma unroll
  for (int i = 0; i < 4; ++i) {
#pragma unroll
    for (int r = 0; r < 4; ++r) {
      const int m = m0 + mw + i * 16 + quad * 4 + r;
      const int b = m >> 11, s = m & 2047;
      const int rowidx = ((b << 2) + h) * Ssz + s;
      const float inv = 1.f / (dens[rowidx] + 1e-6f);
#pragma unroll
      for (int j = 0; j < 4; ++j) {
        const int e = e0t + ew + j * 16 + l15;
        const float av = acc[i][j][r] * inv;
        if (mode == 0) {
          const float a = At[(size_t)rowidx * HDsz + e];
          bfout[(size_t)m * Dsz + h * HDsz + e] = f2b(g * av + (1.f - g) * a);
        } else {
          float* p = Vio + (size_t)m * Dsz + h * HDsz + e;
          *p = *p - av;
        }
      }
    }
  }
}

// ---------------------------------------------------------------------------
// mem partials: P[(h*16+chunk)][d][e] = sum_{m in chunk} sk[m,h*256+d]*W[m,h*256+e]
// bf16 MFMA TN GEMM; both operands transposed during staging (reg 4x4
// transpose + ds_write_b64, m-fast lane map: conflict-free LDS, 128B global).
// grid (4 de-tiles, 4 heads, 16 chunks of 512 rows), 256 threads.
// ---------------------------------------------------------------------------
__global__ __launch_bounds__(256) void mem_update_mfma(const float* __restrict__ SK,
                                                       const float* __restrict__ W,
                                                       float* __restrict__ P) {
  const int de = blockIdx.x;
  const int d0 = (de >> 1) * 128, e0 = (de & 1) * 128;
  const int h = blockIdx.y, chunk = blockIdx.z;
  const int m0 = chunk * 512;
  const int tid = threadIdx.x, lane = tid & 63, w = tid >> 6;
  const int quad = lane >> 4, l15 = lane & 15;
  const int dw = (w >> 1) * 64, ew = (w & 1) * 64;
  __shared__ u16 sA[128 * 40];  // [d][m]
  __shared__ u16 sB[128 * 40];  // [e][m]
  const int m4 = (tid & 7) * 4;   // m sub-rows (fast over lanes)
  const int c4 = (tid >> 3) * 4;  // d/e column group
  f32x4 acc[4][4] = {};
  for (int mt = 0; mt < 512; mt += 32) {
    __syncthreads();
    const float* ka = SK + (size_t)(m0 + mt + m4) * Dsz + h * HDsz + d0 + c4;
    const float* wa = W + (size_t)(m0 + mt + m4) * Dsz + h * HDsz + e0 + c4;
    float4 a0 = *(const float4*)ka;
    float4 a1 = *(const float4*)(ka + Dsz);
    float4 a2 = *(const float4*)(ka + 2 * Dsz);
    float4 a3 = *(const float4*)(ka + 3 * Dsz);
    float4 b0 = *(const float4*)wa;
    float4 b1 = *(const float4*)(wa + Dsz);
    float4 b2 = *(const float4*)(wa + 2 * Dsz);
    float4 b3 = *(const float4*)(wa + 3 * Dsz);
    const float* aa[4] = {(const float*)&a0, (const float*)&a1,
                          (const float*)&a2, (const float*)&a3};
    const float* bb[4] = {(const float*)&b0, (const float*)&b1,
                          (const float*)&b2, (const float*)&b3};
#pragma unroll
    for (int c = 0; c < 4; ++c) {
      uint2 ua, ub2;
      ua.x = pk2(aa[0][c], aa[1][c]); ua.y = pk2(aa[2][c], aa[3][c]);
      ub2.x = pk2(bb[0][c], bb[1][c]); ub2.y = pk2(bb[2][c], bb[3][c]);
      *(uint2*)&sA[(c4 + c) * 40 + m4] = ua;
      *(uint2*)&sB[(c4 + c) * 40 + m4] = ub2;
    }
    __syncthreads();
    bf16x8 af[4], bfr[4];
#pragma unroll
    for (int i = 0; i < 4; ++i) {
      af[i] = *(const bf16x8*)&sA[(dw + i * 16 + l15) * 40 + quad * 8];
      bfr[i] = *(const bf16x8*)&sB[(ew + i * 16 + l15) * 40 + quad * 8];
    }
#pragma unroll
    for (int i = 0; i < 4; ++i)
#pragma unroll
      for (int j = 0; j < 4; ++j)
        acc[i][j] = __builtin_amdgcn_mfma_f32_16x16x32_bf16(af[i], bfr[j], acc[i][j], 0, 0, 0);
  }
  float* Pp = P + ((size_t)(h * 16 + chunk)) * 65536;
#pragma unroll
  for (int i = 0; i < 4; ++i)
#pragma unroll
    for (int r = 0; r < 4; ++r) {
      const int d = d0 + dw + i * 16 + quad * 4 + r;
#pragma unroll
      for (int j = 0; j < 4; ++j) {
        const int e = e0 + ew + j * 16 + l15;
        Pp[(size_t)d * HDsz + e] = acc[i][j][r];
      }
    }
}

// ---------------------------------------------------------------------------
// outmem = mem + 0.25 * sum_{chunk} P[h*16+chunk]
// ---------------------------------------------------------------------------
__global__ __launch_bounds__(256) void mem_reduce(const float4* __restrict__ P,
                                                  const float4* __restrict__ mem,
                                                  float4* __restrict__ outmem) {
  const int gid = blockIdx.x * 256 + threadIdx.x;  // 0..65535 float4s
  const int h = gid >> 14, off = gid & 16383;
  float sx = 0.f, sy = 0.f, sz = 0.f, sw = 0.f;
#pragma unroll 4
  for (int c = 0; c < 16; ++c) {
    float4 v = P[((size_t)(h * 16 + c) << 14) + off];
    sx += v.x; sy += v.y; sz += v.z; sw += v.w;
  }
  float4 m = mem[gid];
  float4 o;
  o.x = m.x + 0.25f * sx; o.y = m.y + 0.25f * sy;
  o.z = m.z + 0.25f * sz; o.w = m.w + 0.25f * sw;
  outmem[gid] = o;
}

// ---------------------------------------------------------------------------
// z_new[h][d] = z[h][d] + (1/B) sum_{b,s} sk[b,h,s,d]
// ---------------------------------------------------------------------------
__global__ __launch_bounds__(256) void z_update(const float* __restrict__ SK,
                                                const float* __restrict__ z_in,
                                                float* __restrict__ z_out) {
  const int h = blockIdx.x >> 4, chunk = blockIdx.x & 15;
  const int t = threadIdx.x;
  const int m0 = chunk * 512;
  float sum = 0.f;
  for (int i = 0; i < 512; ++i) sum += SK[(size_t)(m0 + i) * Dsz + h * HDsz + t];
  float val = sum * 0.25f;
  if (chunk == 0) val += z_in[h * HDsz + t];
  atomicAdd(z_out + h * HDsz + t, val);
}

// ---------------------------------------------------------------------------
extern "C" void kernel_launch(void* const* d_in, const int* in_sizes, int n_in,
                              void* d_out, int out_size, void* d_ws, size_t ws_size,
                              hipStream_t stream) {
  (void)in_sizes; (void)n_in; (void)out_size; (void)ws_size;
  const float* Hs = (const float*)d_in[0];
  const float* Wq = (const float*)d_in[1];
  const float* Wk = (const float*)d_in[2];
  const float* Wv = (const float*)d_in[3];
  const float* Wo = (const float*)d_in[4];
  const float* bo = (const float*)d_in[5];
  const float* betas = (const float*)d_in[6];
  const float* mem = (const float*)d_in[7];
  const float* z = (const float*)d_in[8];

  // fp32 workspace region (134.5 MB)
  float* ws = (float*)d_ws;
  float* Qb = ws;                   // 8388608 : Q fp32 -> sq
  float* Kb = ws + 8388608;         // K fp32 -> sk
  float* Vb = ws + 16777216;        // V fp32 -> W = v - delta
  float* At = ws + 25165824;        // attn out fp32 [bh][s][e]
  float* dq = ws + 33554432;        // 32768
  float* dk = ws + 33554432 + 32768;
  // bf16 region (58.7 MB)
  u16* ub = (u16*)(ws + 33554432 + 65536);
  u16* Wqb = ub;                    // 4 x 1048576 weight copies
  u16* Wkb = ub + 1048576;
  u16* Wvb = ub + 2097152;
  u16* Wob = ub + 3145728;
  u16* Qbf = ub + 4194304;          // bf16 Q; later reused as bf16 blend
  u16* Kbf = ub + 4194304 + 8388608;
  u16* Vt = ub + 4194304 + 16777216;  // V^T bf16 [bh][e][s]; dead after attn
  float* P = (float*)Vt;            // mem partials alias (16.8 MB, 64 x 65536 f32)

  float* out = (float*)d_out;                 // 8192x1024
  float* outmem = out + (size_t)Msz * Dsz;    // 4x256x256
  float* outz = outmem + Hsz * HDsz * HDsz;   // 4x256

  hipMemsetAsync(outz, 0, (size_t)(Hsz * HDsz) * sizeof(float), stream);

  cvt_bf16<<<1024, 256, 0, stream>>>((const float4*)Wq, Wqb);
  cvt_bf16<<<1024, 256, 0, stream>>>((const float4*)Wk, Wkb);
  cvt_bf16<<<1024, 256, 0, stream>>>((const float4*)Wv, Wvb);
  cvt_bf16<<<1024, 256, 0, stream>>>((const float4*)Wo, Wob);

  dim3 gg(8, 64);  // N/128, M/128
  gemm_mfma<true><<<gg, 256, 0, stream>>>(Hs, nullptr, Wqb, nullptr, Qb, Qbf);
  gemm_mfma<true><<<gg, 256, 0, stream>>>(Hs, nullptr, Wkb, nullptr, Kb, Kbf);
  gemm_mfma<true><<<gg, 256, 0, stream>>>(Hs, nullptr, Wvb, nullptr, Vb, nullptr);

  transpose_v<<<dim3(64, 8, 16), 256, 0, stream>>>(Vb, Vt);
  attn_mfma<<<dim3(32, 16), 256, 0, stream>>>(Qbf, Kbf, Vt, At);

  elu1_kernel<<<8192, 256, 0, stream>>>((float4*)Qb, (float4*)Kb);
  dens_kernel<<<8192, 256, 0, stream>>>(Qb, Kb, z, dq, dk);

  // blend -> bf16 into Qbf (bf16 Q dead after attn); W -> Vb in place
  memread_mfma<<<dim3(2, 64, 4), 256, 0, stream>>>(Qb, mem, dq, betas, At, nullptr, Qbf, 0);
  memread_mfma<<<dim3(2, 64, 4), 256, 0, stream>>>(Kb, mem, dk, betas, nullptr, Vb, nullptr, 1);

  mem_update_mfma<<<dim3(4, 4, 16), 256, 0, stream>>>(Kb, Vb, P);
  mem_reduce<<<256, 256, 0, stream>>>((const float4*)P, (const float4*)mem, (float4*)outmem);
  z_update<<<64, 256, 0, stream>>>(Kb, z, outz);

  gemm_mfma<false><<<gg, 256, 0, stream>>>(nullptr, Qbf, Wob, bo, out, nullptr);
}

// Round 4
// 577.375 us; speedup vs baseline: 4.8039x; 1.1345x over previous
//
#include <hip/hip_runtime.h>

// Problem constants (B,S,D,H fixed by the reference)
#define Bsz 4
#define Ssz 2048
#define Dsz 1024
#define Hsz 4
#define HDsz 256
#define Msz 8192  // Bsz*Ssz

typedef unsigned short u16;
typedef __attribute__((ext_vector_type(8))) short bf16x8;  // 8 bf16 in 4 VGPRs
typedef __attribute__((ext_vector_type(4))) float f32x4;

__device__ __forceinline__ u16 f2b(float f) {  // fp32 -> bf16 RNE
  unsigned u = __float_as_uint(f);
  return (u16)((u + 0x7FFFu + ((u >> 16) & 1u)) >> 16);
}
__device__ __forceinline__ unsigned pk2(float a, float b) {
  return (unsigned)f2b(a) | ((unsigned)f2b(b) << 16);
}

// async global->LDS, 16B per lane; LDS dest = wave-uniform base + lane*16
typedef const unsigned int __attribute__((address_space(1)))* gcp;
typedef unsigned int __attribute__((address_space(3)))* lcp;
__device__ __forceinline__ void gld16(const u16* g, u16* l) {
  __builtin_amdgcn_global_load_lds((gcp)g, (lcp)l, 16, 0, 0);
}

// ---------------------------------------------------------------------------
// fp32 -> bf16 elementwise
// ---------------------------------------------------------------------------
__global__ __launch_bounds__(256) void cvt_bf16(const float4* __restrict__ in,
                                                u16* __restrict__ outp) {
  size_t i = (size_t)blockIdx.x * 256 + threadIdx.x;
  float4 v = in[i];
  uint2 r; r.x = pk2(v.x, v.y); r.y = pk2(v.z, v.w);
  *(uint2*)(outp + i * 4) = r;
}

// ---------------------------------------------------------------------------
// bf16 MFMA GEMM (m97 structure): C[M,N] = A[M,K]*W[N,K]^T (+bias).
// 128x128 tile, BK=32, global_load_lds width-16 staging, unpadded [128][32]
// LDS. 4 waves x (4x4 of 16x16x32 MFMA). M=8192, N=K=1024.
// ---------------------------------------------------------------------------
__global__ __launch_bounds__(256) void gemm_lds(const u16* __restrict__ A16,
                                                const u16* __restrict__ Wb,
                                                const float* __restrict__ bias,
                                                float* __restrict__ C32,
                                                u16* __restrict__ Cbf) {
  __shared__ u16 sA[128 * 32];
  __shared__ u16 sB[128 * 32];
  const int tid = threadIdx.x;
  const int lane = tid & 63, quad = lane >> 4, l15 = lane & 15;
  const int w = tid >> 6;
  const int mw = (w >> 1) * 64, nw = (w & 1) * 64;
  const int m0 = blockIdx.y * 128, n0 = blockIdx.x * 128;
  const int r0 = tid >> 2, seg = (tid & 3) * 8;  // 4 lanes x 16B per row
  const u16* ga0 = A16 + (size_t)(m0 + r0) * Dsz + seg;
  const u16* gb0 = Wb + (size_t)(n0 + r0) * Dsz + seg;
  u16* lA0 = sA + w * 512;          // wave-uniform bases (u16 units)
  u16* lA1 = sA + 2048 + w * 512;
  u16* lB0 = sB + w * 512;
  u16* lB1 = sB + 2048 + w * 512;
  f32x4 acc[4][4] = {};
  for (int k0 = 0; k0 < Dsz; k0 += 32) {
    __syncthreads();
    gld16(ga0 + k0, lA0);
    gld16(ga0 + (size_t)64 * Dsz + k0, lA1);
    gld16(gb0 + k0, lB0);
    gld16(gb0 + (size_t)64 * Dsz + k0, lB1);
    __syncthreads();  // compiler drains vmcnt before barrier
    bf16x8 af[4], bfr[4];
#pragma unroll
    for (int i = 0; i < 4; ++i) {
      af[i] = *(const bf16x8*)&sA[(mw + i * 16 + l15) * 32 + quad * 8];
      bfr[i] = *(const bf16x8*)&sB[(nw + i * 16 + l15) * 32 + quad * 8];
    }
#pragma unroll
    for (int i = 0; i < 4; ++i)
#pragma unroll
      for (int j = 0; j < 4; ++j)
        acc[i][j] = __builtin_amdgcn_mfma_f32_16x16x32_bf16(af[i], bfr[j], acc[i][j], 0, 0, 0);
  }
#pragma unroll
  for (int j = 0; j < 4; ++j) {
    const int n = n0 + nw + j * 16 + l15;
    const float bv = bias ? bias[n] : 0.f;
#pragma unroll
    for (int i = 0; i < 4; ++i) {
#pragma unroll
      for (int r = 0; r < 4; ++r) {
        const int m = m0 + mw + i * 16 + quad * 4 + r;
        const float val = acc[i][j][r] + bv;
        const size_t idx = (size_t)m * Dsz + n;
        if (C32) C32[idx] = val;
        if (Cbf) Cbf[idx] = f2b(val);
      }
    }
  }
}

// ---------------------------------------------------------------------------
// V [b][s][h*256+e] fp32 -> V^T bf16 [bh][e][s]
// ---------------------------------------------------------------------------
__global__ __launch_bounds__(256) void transpose_v(const float* __restrict__ V,
                                                   u16* __restrict__ Vt) {
  __shared__ u16 tile[32 * 36];
  const int t = threadIdx.x;
  const int s0 = blockIdx.x * 32, e0 = blockIdx.y * 32, bh = blockIdx.z;
  const int b = bh >> 2, h = bh & 3;
  {
    const int s_l = t >> 3, e8 = (t & 7) * 4;
    float4 v = *(const float4*)(V + ((size_t)(b * Ssz) + s0 + s_l) * Dsz + h * HDsz + e0 + e8);
    uint2 r; r.x = pk2(v.x, v.y); r.y = pk2(v.z, v.w);
    *(uint2*)&tile[s_l * 36 + e8] = r;
  }
  __syncthreads();
  {
    const int e_l = t >> 3, s4 = (t & 7) * 4;
    u16 a = tile[(s4 + 0) * 36 + e_l], b2 = tile[(s4 + 1) * 36 + e_l];
    u16 c = tile[(s4 + 2) * 36 + e_l], d = tile[(s4 + 3) * 36 + e_l];
    uint2 r; r.x = (unsigned)a | ((unsigned)b2 << 16);
    r.y = (unsigned)c | ((unsigned)d << 16);
    *(uint2*)(Vt + ((size_t)bh * HDsz + e0 + e_l) * Ssz + s0 + s4) = r;
  }
}

// ---------------------------------------------------------------------------
// Flash attention, bf16 MFMA, flash-decoding split-K.
// blockIdx.x in [0,52): x<40 -> split qt = 12+(x>>1), chunk = x&1 (heavy
// chunks dispatched first); x>=40 -> single-chunk qt = x-40 (0..11).
// Split chunks write unnormalized O + (m,l); attn_merge combines.
// ---------------------------------------------------------------------------
__global__ __launch_bounds__(256) void attn_mfma(const u16* __restrict__ Qg,
                                                 const u16* __restrict__ Kg,
                                                 const u16* __restrict__ Vtg,
                                                 float* __restrict__ At,
                                                 float* __restrict__ Pb,
                                                 float* __restrict__ mlb) {
  const int x = blockIdx.x;
  int qt, cc; bool split;
  if (x < 40) { qt = 12 + (x >> 1); cc = x & 1; split = true; }
  else { qt = x - 40; cc = 0; split = false; }
  const int bh = blockIdx.y, b = bh >> 2, h = bh & 3;
  const int tid = threadIdx.x, w = tid >> 6, lane = tid & 63;
  const int quad = lane >> 4, l15 = lane & 15;
  __shared__ u16 sK[32 * 264];
  __shared__ u16 sV[256 * 40];
  const int q0w = qt * 64 + w * 16;
  bf16x8 qf[8];
  {
    const u16* qp = Qg + ((size_t)(b * Ssz) + q0w + l15) * Dsz + h * HDsz + quad * 8;
#pragma unroll
    for (int dd = 0; dd < 8; ++dd) qf[dd] = *(const bf16x8*)(qp + dd * 32);
  }
  f32x4 o[16] = {};
  float m_old = -1e30f, l = 0.f;
  const int nkt = 2 * qt + 2, half = qt + 1;
  const int kt_lo = (split && cc) ? half : 0;
  const int kt_hi = (split && !cc) ? half : nkt;
  const int krow = tid >> 3, kseg = (tid & 7) * 32;
  const u16* kbase = Kg + ((size_t)(b * Ssz) + krow) * Dsz + h * HDsz + kseg;
  const u16* vbase = Vtg + ((size_t)bh * HDsz + tid) * Ssz;
  for (int kt = kt_lo; kt < kt_hi; ++kt) {
    const int j0 = kt * 32;
    __syncthreads();
    {
      const u16* kp = kbase + (size_t)j0 * Dsz;
      u16* dkp = &sK[krow * 264 + kseg];
#pragma unroll
      for (int i = 0; i < 4; ++i) *(uint4*)(dkp + i * 8) = *(const uint4*)(kp + i * 8);
      const u16* vp = vbase + j0;
      u16* dvp = &sV[tid * 40];
#pragma unroll
      for (int i = 0; i < 4; ++i) *(uint4*)(dvp + i * 8) = *(const uint4*)(vp + i * 8);
    }
    __syncthreads();
    f32x4 s0v = {}, s1v = {};
#pragma unroll
    for (int dd = 0; dd < 8; ++dd) {
      bf16x8 a0 = *(const bf16x8*)&sK[l15 * 264 + dd * 32 + quad * 8];
      bf16x8 a1 = *(const bf16x8*)&sK[(16 + l15) * 264 + dd * 32 + quad * 8];
      s0v = __builtin_amdgcn_mfma_f32_16x16x32_bf16(a0, qf[dd], s0v, 0, 0, 0);
      s1v = __builtin_amdgcn_mfma_f32_16x16x32_bf16(a1, qf[dd], s1v, 0, 0, 0);
    }
    const int qg = q0w + l15;
    float p[8];
#pragma unroll
    for (int r = 0; r < 4; ++r) {
      const int kg = j0 + quad * 4 + r;
      p[r] = (kg <= qg) ? s0v[r] : -1e30f;
      p[4 + r] = (kg + 16 <= qg) ? s1v[r] : -1e30f;
    }
    float mt = p[0];
#pragma unroll
    for (int i = 1; i < 8; ++i) mt = fmaxf(mt, p[i]);
    mt = fmaxf(mt, __shfl_xor(mt, 16));
    mt = fmaxf(mt, __shfl_xor(mt, 32));
    const float m_new = fmaxf(m_old, mt);
    const float alpha = __expf(m_old - m_new);
    float ts = 0.f;
#pragma unroll
    for (int i = 0; i < 8; ++i) { p[i] = __expf(p[i] - m_new); ts += p[i]; }
    ts += __shfl_xor(ts, 16);
    ts += __shfl_xor(ts, 32);
    l = l * alpha + ts;
    m_old = m_new;
    if (!__all(alpha == 1.0f)) {
      const float a0_ = __shfl(alpha, (lane & 48) | (quad * 4 + 0));
      const float a1_ = __shfl(alpha, (lane & 48) | (quad * 4 + 1));
      const float a2_ = __shfl(alpha, (lane & 48) | (quad * 4 + 2));
      const float a3_ = __shfl(alpha, (lane & 48) | (quad * 4 + 3));
#pragma unroll
      for (int ds = 0; ds < 16; ++ds) {
        o[ds][0] *= a0_; o[ds][1] *= a1_; o[ds][2] *= a2_; o[ds][3] *= a3_;
      }
    }
    float xx[8];
#pragma unroll
    for (int i = 0; i < 8; ++i) xx[i] = __shfl_xor(p[i], 16);
    const bool qe = (quad & 1) == 0;
    float Alo[8], Ahi[8];
#pragma unroll
    for (int i = 0; i < 4; ++i) {
      Alo[i] = qe ? p[i] : xx[i];
      Alo[4 + i] = qe ? xx[i] : p[i];
      Ahi[i] = qe ? p[4 + i] : xx[4 + i];
      Ahi[4 + i] = qe ? xx[4 + i] : p[4 + i];
    }
    float zz[8];
    const bool sendlo = (quad & 1) != 0;
#pragma unroll
    for (int i = 0; i < 8; ++i) zz[i] = __shfl_xor(sendlo ? Alo[i] : Ahi[i], 32);
    float fin[8];
#pragma unroll
    for (int i = 0; i < 8; ++i)
      fin[i] = (quad == 0) ? Alo[i] : (quad == 3) ? Ahi[i] : zz[i];
    uint4 pkv;
    pkv.x = pk2(fin[0], fin[1]); pkv.y = pk2(fin[2], fin[3]);
    pkv.z = pk2(fin[4], fin[5]); pkv.w = pk2(fin[6], fin[7]);
    bf16x8 pf = *(bf16x8*)&pkv;
#pragma unroll
    for (int ds = 0; ds < 16; ++ds) {
      bf16x8 bv = *(const bf16x8*)&sV[(ds * 16 + l15) * 40 + quad * 8];
      o[ds] = __builtin_amdgcn_mfma_f32_16x16x32_bf16(pf, bv, o[ds], 0, 0, 0);
    }
  }
  if (!split) {
    float lr[4];
#pragma unroll
    for (int r = 0; r < 4; ++r) lr[r] = 1.f / __shfl(l, (lane & 48) | (quad * 4 + r));
    float* ob = At + ((size_t)bh * Ssz + q0w + quad * 4) * HDsz + l15;
#pragma unroll
    for (int r = 0; r < 4; ++r)
#pragma unroll
      for (int ds = 0; ds < 16; ++ds)
        ob[(size_t)r * HDsz + ds * 16] = o[ds][r] * lr[r];
  } else {
    float* dst;
    if (cc == 0)
      dst = At + ((size_t)bh * Ssz + q0w + quad * 4) * HDsz + l15;
    else
      dst = Pb + ((size_t)((bh * 20 + (qt - 12)) * 64) + w * 16 + quad * 4) * HDsz + l15;
#pragma unroll
    for (int r = 0; r < 4; ++r)
#pragma unroll
      for (int ds = 0; ds < 16; ++ds)
        dst[(size_t)r * HDsz + ds * 16] = o[ds][r];
    if (lane < 16) {
      const int idx = (bh * 20 + (qt - 12)) * 64 + w * 16 + l15;
      mlb[cc * 40960 + idx] = m_old;
      mlb[cc * 40960 + 20480 + idx] = l;
    }
  }
}

// ---------------------------------------------------------------------------
// Merge the two split-K chunks for qt>=12: O = (O0*e^{m0-m}+O1*e^{m1-m}) /
// (l0*e^{m0-m}+l1*e^{m1-m}).  grid (20, 16).
// ---------------------------------------------------------------------------
__global__ __launch_bounds__(256) void attn_merge(float* __restrict__ At,
                                                  const float* __restrict__ Pb,
                                                  const float* __restrict__ mlb) {
  const int qx = blockIdx.x, bh = blockIdx.y;
  const int t = threadIdx.x;
  const int slot = (bh * 20 + qx) * 64;
  float4* abase = (float4*)(At + ((size_t)bh * Ssz + (12 + qx) * 64) * HDsz);
  const float4* pbase = (const float4*)(Pb + (size_t)slot * HDsz);
#pragma unroll
  for (int i = 0; i < 16; ++i) {
    const int f = i * 256 + t;  // f4 index 0..4095, coalesced
    const int qr = f >> 6;
    const int idx = slot + qr;
    const float m0 = mlb[idx], l0 = mlb[20480 + idx];
    const float m1 = mlb[40960 + idx], l1 = mlb[61440 + idx];
    const float mm = fmaxf(m0, m1);
    const float w0 = __expf(m0 - mm), w1 = __expf(m1 - mm);
    const float inv = 1.f / (l0 * w0 + l1 * w1);
    float4 av = abase[f];
    float4 pv = pbase[f];
    float4 ov;
    ov.x = (av.x * w0 + pv.x * w1) * inv;
    ov.y = (av.y * w0 + pv.y * w1) * inv;
    ov.z = (av.z * w0 + pv.z * w1) * inv;
    ov.w = (av.w * w0 + pv.w * w1) * inv;
    abase[f] = ov;
  }
}

// ---------------------------------------------------------------------------
// Fused: sq=elu(q)+1, sk=elu(k)+1 (in place) + denq = sq.z, denk = sk.z.
// One wave per row; grid 8192 x 256.
// ---------------------------------------------------------------------------
__global__ __launch_bounds__(256) void eludens(float* __restrict__ Qb,
                                               float* __restrict__ Kb,
                                               const float* __restrict__ z,
                                               float* __restrict__ dq,
                                               float* __restrict__ dk) {
  const int wid = threadIdx.x >> 6, lane = threadIdx.x & 63;
  const int r = blockIdx.x * 4 + wid;
  const int b = r >> 13, h = (r >> 11) & 3, s = r & 2047;
  const size_t base = ((size_t)(b * Ssz + s)) * Dsz + h * HDsz + lane * 4;
  float4 z4 = *(const float4*)(z + h * HDsz + lane * 4);
  float4 q = *(float4*)(Qb + base);
  q.x = q.x > 0.f ? q.x + 1.f : __expf(q.x);
  q.y = q.y > 0.f ? q.y + 1.f : __expf(q.y);
  q.z = q.z > 0.f ? q.z + 1.f : __expf(q.z);
  q.w = q.w > 0.f ? q.w + 1.f : __expf(q.w);
  *(float4*)(Qb + base) = q;
  float4 k = *(float4*)(Kb + base);
  k.x = k.x > 0.f ? k.x + 1.f : __expf(k.x);
  k.y = k.y > 0.f ? k.y + 1.f : __expf(k.y);
  k.z = k.z > 0.f ? k.z + 1.f : __expf(k.z);
  k.w = k.w > 0.f ? k.w + 1.f : __expf(k.w);
  *(float4*)(Kb + base) = k;
  float pq = q.x * z4.x + q.y * z4.y + q.z * z4.z + q.w * z4.w;
  float pk = k.x * z4.x + k.y * z4.y + k.z * z4.z + k.w * z4.w;
#pragma unroll
  for (int off = 32; off; off >>= 1) {
    pq += __shfl_down(pq, off);
    pk += __shfl_down(pk, off);
  }
  if (lane == 0) { dq[r] = pq; dk[r] = pk; }
}

// ---------------------------------------------------------------------------
// Per-head MFMA GEMM: acc[m,e] = sum_d Asrc[m,h*256+d] * mem[h][d][e].
// mode 0: blend = g*acc/den + (1-g)*At -> bf16 row-major (bfout)
// mode 1: Vio = v - acc/den (fp32 in place)
// ---------------------------------------------------------------------------
__global__ __launch_bounds__(256) void memread_mfma(const float* __restrict__ Asrc,
                                                    const float* __restrict__ mem,
                                                    const float* __restrict__ dens,
                                                    const float* __restrict__ betas,
                                                    const float* __restrict__ At,
                                                    float* __restrict__ Vio,
                                                    u16* __restrict__ bfout, int mode) {
  const int h = blockIdx.z;
  const int tid = threadIdx.x, lane = tid & 63, w = tid >> 6;
  const int quad = lane >> 4, l15 = lane & 15;
  const int mw = (w >> 1) * 64, ew = (w & 1) * 64;
  const int m0 = blockIdx.y * 128, e0t = blockIdx.x * 128;
  __shared__ u16 sA[128 * 40];  // [m][k]
  __shared__ u16 sB[128 * 40];  // [e][k]
  const int srow = tid >> 1, sseg = (tid & 1) * 16;
  const int k4 = (tid & 7) * 4, e4 = (tid >> 3) * 4;
  f32x4 acc[4][4] = {};
  for (int k0 = 0; k0 < HDsz; k0 += 32) {
    __syncthreads();
    {
      const float* ap = Asrc + (size_t)(m0 + srow) * Dsz + h * HDsz + k0 + sseg;
      float4 f0 = *(const float4*)ap, f1 = *(const float4*)(ap + 4);
      float4 f2 = *(const float4*)(ap + 8), f3 = *(const float4*)(ap + 12);
      uint4 u0, u1;
      u0.x = pk2(f0.x, f0.y); u0.y = pk2(f0.z, f0.w);
      u0.z = pk2(f1.x, f1.y); u0.w = pk2(f1.z, f1.w);
      u1.x = pk2(f2.x, f2.y); u1.y = pk2(f2.z, f2.w);
      u1.z = pk2(f3.x, f3.y); u1.w = pk2(f3.z, f3.w);
      u16* dst = &sA[srow * 40 + sseg];
      *(uint4*)dst = u0; *(uint4*)(dst + 8) = u1;
    }
    {
      const float* bp = mem + (size_t)h * 65536 + (size_t)(k0 + k4) * HDsz + e0t + e4;
      float4 r0 = *(const float4*)bp;
      float4 r1 = *(const float4*)(bp + HDsz);
      float4 r2 = *(const float4*)(bp + 2 * HDsz);
      float4 r3 = *(const float4*)(bp + 3 * HDsz);
      const float* rr[4] = {(const float*)&r0, (const float*)&r1,
                            (const float*)&r2, (const float*)&r3};
#pragma unroll
      for (int c = 0; c < 4; ++c) {
        uint2 u;
        u.x = pk2(rr[0][c], rr[1][c]);
        u.y = pk2(rr[2][c], rr[3][c]);
        *(uint2*)&sB[(e4 + c) * 40 + k4] = u;
      }
    }
    __syncthreads();
    bf16x8 af[4], bfr[4];
#pragma unroll
    for (int i = 0; i < 4; ++i) {
      af[i] = *(const bf16x8*)&sA[(mw + i * 16 + l15) * 40 + quad * 8];
      bfr[i] = *(const bf16x8*)&sB[(ew + i * 16 + l15) * 40 + quad * 8];
    }
#pragma unroll
    for (int i = 0; i < 4; ++i)
#pragma unroll
      for (int j = 0; j < 4; ++j)
        acc[i][j] = __builtin_amdgcn_mfma_f32_16x16x32_bf16(af[i], bfr[j], acc[i][j], 0, 0, 0);
  }
  const float g = 1.f / (1.f + __expf(-betas[h]));
#pragma unroll
  for (int i = 0; i < 4; ++i) {
#pragma unroll
    for (int r = 0; r < 4; ++r) {
      const int m = m0 + mw + i * 16 + quad * 4 + r;
      const int b = m >> 11, s = m & 2047;
      const int rowidx = ((b << 2) + h) * Ssz + s;
      const float inv = 1.f / (dens[rowidx] + 1e-6f);
#pragma unroll
      for (int j = 0; j < 4; ++j) {
        const int e = e0t + ew + j * 16 + l15;
        const float av = acc[i][j][r] * inv;
        if (mode == 0) {
          const float a = At[(size_t)rowidx * HDsz + e];
          bfout[(size_t)m * Dsz + h * HDsz + e] = f2b(g * av + (1.f - g) * a);
        } else {
          float* p = Vio + (size_t)m * Dsz + h * HDsz + e;
          *p = *p - av;
        }
      }
    }
  }
}

// ---------------------------------------------------------------------------
// mem partials: P[(h*16+chunk)][d][e] = sum_{m in chunk} sk[m,..d]*W[m,..e]
// ---------------------------------------------------------------------------
__global__ __launch_bounds__(256) void mem_update_mfma(const float* __restrict__ SK,
                                                       const float* __restrict__ W,
                                                       float* __restrict__ P) {
  const int de = blockIdx.x;
  const int d0 = (de >> 1) * 128, e0 = (de & 1) * 128;
  const int h = blockIdx.y, chunk = blockIdx.z;
  const int m0 = chunk * 512;
  const int tid = threadIdx.x, lane = tid & 63, w = tid >> 6;
  const int quad = lane >> 4, l15 = lane & 15;
  const int dw = (w >> 1) * 64, ew = (w & 1) * 64;
  __shared__ u16 sA[128 * 40];  // [d][m]
  __shared__ u16 sB[128 * 40];  // [e][m]
  const int m4 = (tid & 7) * 4;
  const int c4 = (tid >> 3) * 4;
  f32x4 acc[4][4] = {};
  for (int mt = 0; mt < 512; mt += 32) {
    __syncthreads();
    const float* ka = SK + (size_t)(m0 + mt + m4) * Dsz + h * HDsz + d0 + c4;
    const float* wa = W + (size_t)(m0 + mt + m4) * Dsz + h * HDsz + e0 + c4;
    float4 a0 = *(const float4*)ka;
    float4 a1 = *(const float4*)(ka + Dsz);
    float4 a2 = *(const float4*)(ka + 2 * Dsz);
    float4 a3 = *(const float4*)(ka + 3 * Dsz);
    float4 b0 = *(const float4*)wa;
    float4 b1 = *(const float4*)(wa + Dsz);
    float4 b2 = *(const float4*)(wa + 2 * Dsz);
    float4 b3 = *(const float4*)(wa + 3 * Dsz);
    const float* aa[4] = {(const float*)&a0, (const float*)&a1,
                          (const float*)&a2, (const float*)&a3};
    const float* bb[4] = {(const float*)&b0, (const float*)&b1,
                          (const float*)&b2, (const float*)&b3};
#pragma unroll
    for (int c = 0; c < 4; ++c) {
      uint2 ua, ub2;
      ua.x = pk2(aa[0][c], aa[1][c]); ua.y = pk2(aa[2][c], aa[3][c]);
      ub2.x = pk2(bb[0][c], bb[1][c]); ub2.y = pk2(bb[2][c], bb[3][c]);
      *(uint2*)&sA[(c4 + c) * 40 + m4] = ua;
      *(uint2*)&sB[(c4 + c) * 40 + m4] = ub2;
    }
    __syncthreads();
    bf16x8 af[4], bfr[4];
#pragma unroll
    for (int i = 0; i < 4; ++i) {
      af[i] = *(const bf16x8*)&sA[(dw + i * 16 + l15) * 40 + quad * 8];
      bfr[i] = *(const bf16x8*)&sB[(ew + i * 16 + l15) * 40 + quad * 8];
    }
#pragma unroll
    for (int i = 0; i < 4; ++i)
#pragma unroll
      for (int j = 0; j < 4; ++j)
        acc[i][j] = __builtin_amdgcn_mfma_f32_16x16x32_bf16(af[i], bfr[j], acc[i][j], 0, 0, 0);
  }
  float* Pp = P + ((size_t)(h * 16 + chunk)) * 65536;
#pragma unroll
  for (int i = 0; i < 4; ++i)
#pragma unroll
    for (int r = 0; r < 4; ++r) {
      const int d = d0 + dw + i * 16 + quad * 4 + r;
#pragma unroll
      for (int j = 0; j < 4; ++j) {
        const int e = e0 + ew + j * 16 + l15;
        Pp[(size_t)d * HDsz + e] = acc[i][j][r];
      }
    }
}

// ---------------------------------------------------------------------------
// outmem = mem + 0.25 * sum_{chunk} P[h*16+chunk]
// ---------------------------------------------------------------------------
__global__ __launch_bounds__(256) void mem_reduce(const float4* __restrict__ P,
                                                  const float4* __restrict__ mem,
                                                  float4* __restrict__ outmem) {
  const int gid = blockIdx.x * 256 + threadIdx.x;
  const int h = gid >> 14, off = gid & 16383;
  float sx = 0.f, sy = 0.f, sz = 0.f, sw = 0.f;
#pragma unroll 4
  for (int c = 0; c < 16; ++c) {
    float4 v = P[((size_t)(h * 16 + c) << 14) + off];
    sx += v.x; sy += v.y; sz += v.z; sw += v.w;
  }
  float4 m = mem[gid];
  float4 o;
  o.x = m.x + 0.25f * sx; o.y = m.y + 0.25f * sy;
  o.z = m.z + 0.25f * sz; o.w = m.w + 0.25f * sw;
  outmem[gid] = o;
}

// ---------------------------------------------------------------------------
// z_new[h][d] = z[h][d] + (1/B) sum_{b,s} sk[b,h,s,d]
// ---------------------------------------------------------------------------
__global__ __launch_bounds__(256) void z_update(const float* __restrict__ SK,
                                                const float* __restrict__ z_in,
                                                float* __restrict__ z_out) {
  const int h = blockIdx.x >> 4, chunk = blockIdx.x & 15;
  const int t = threadIdx.x;
  const int m0 = chunk * 512;
  float sum = 0.f;
  for (int i = 0; i < 512; ++i) sum += SK[(size_t)(m0 + i) * Dsz + h * HDsz + t];
  float val = sum * 0.25f;
  if (chunk == 0) val += z_in[h * HDsz + t];
  atomicAdd(z_out + h * HDsz + t, val);
}

// ---------------------------------------------------------------------------
extern "C" void kernel_launch(void* const* d_in, const int* in_sizes, int n_in,
                              void* d_out, int out_size, void* d_ws, size_t ws_size,
                              hipStream_t stream) {
  (void)in_sizes; (void)n_in; (void)out_size; (void)ws_size;
  const float* Hs = (const float*)d_in[0];
  const float* Wq = (const float*)d_in[1];
  const float* Wk = (const float*)d_in[2];
  const float* Wv = (const float*)d_in[3];
  const float* Wo = (const float*)d_in[4];
  const float* bo = (const float*)d_in[5];
  const float* betas = (const float*)d_in[6];
  const float* mem = (const float*)d_in[7];
  const float* z = (const float*)d_in[8];

  // fp32 workspace region
  float* ws = (float*)d_ws;
  float* Qb = ws;                    // 8388608 : Q fp32 -> sq
  float* Kb = ws + 8388608;          // K fp32 -> sk
  float* Vb = ws + 16777216;         // V fp32 -> W = v - delta
  float* At = ws + 25165824;         // attn out fp32 [bh][s][e]
  float* dq = ws + 33554432;         // 32768
  float* dk = ws + 33587200;         // 32768
  float* mlb = ws + 33619968;        // 81920 (4 planes x 20480)
  // bf16 region
  u16* ub = (u16*)(ws + 33701888);
  u16* Wqb = ub;                     // 4 x 1048576 weight copies
  u16* Wkb = ub + 1048576;
  u16* Wvb = ub + 2097152;
  u16* Wob = ub + 3145728;
  u16* Qbf = ub + 4194304;           // bf16 Q; later reused as bf16 blend
  u16* Kbf = ub + 12582912;
  u16* Vt = ub + 20971520;           // 8388608 u16: Hs bf16 first, then V^T
  u16* Hsb = Vt;                     // alias: dead once transpose_v runs
  float* P = (float*)Vt;             // mem partials alias (dead after attn)
  float* Pb = (float*)d_out;         // split-attn chunk-1 partials (21 MB),
                                     // written+read before final out GEMM

  float* out = (float*)d_out;                 // 8192x1024
  float* outmem = out + (size_t)Msz * Dsz;    // 4x256x256
  float* outz = outmem + Hsz * HDsz * HDsz;   // 4x256

  hipMemsetAsync(outz, 0, (size_t)(Hsz * HDsz) * sizeof(float), stream);

  cvt_bf16<<<1024, 256, 0, stream>>>((const float4*)Wq, Wqb);
  cvt_bf16<<<1024, 256, 0, stream>>>((const float4*)Wk, Wkb);
  cvt_bf16<<<1024, 256, 0, stream>>>((const float4*)Wv, Wvb);
  cvt_bf16<<<1024, 256, 0, stream>>>((const float4*)Wo, Wob);
  cvt_bf16<<<8192, 256, 0, stream>>>((const float4*)Hs, Hsb);

  dim3 gg(8, 64);  // N/128, M/128
  gemm_lds<<<gg, 256, 0, stream>>>(Hsb, Wqb, nullptr, Qb, Qbf);
  gemm_lds<<<gg, 256, 0, stream>>>(Hsb, Wkb, nullptr, Kb, Kbf);
  gemm_lds<<<gg, 256, 0, stream>>>(Hsb, Wvb, nullptr, Vb, nullptr);

  transpose_v<<<dim3(64, 8, 16), 256, 0, stream>>>(Vb, Vt);
  attn_mfma<<<dim3(52, 16), 256, 0, stream>>>(Qbf, Kbf, Vt, At, Pb, mlb);
  attn_merge<<<dim3(20, 16), 256, 0, stream>>>(At, Pb, mlb);

  eludens<<<8192, 256, 0, stream>>>(Qb, Kb, z, dq, dk);

  memread_mfma<<<dim3(2, 64, 4), 256, 0, stream>>>(Qb, mem, dq, betas, At, nullptr, Qbf, 0);
  memread_mfma<<<dim3(2, 64, 4), 256, 0, stream>>>(Kb, mem, dk, betas, nullptr, Vb, nullptr, 1);

  mem_update_mfma<<<dim3(4, 4, 16), 256, 0, stream>>>(Kb, Vb, P);
  mem_reduce<<<256, 256, 0, stream>>>((const float4*)P, (const float4*)mem, (float4*)outmem);
  z_update<<<64, 256, 0, stream>>>(Kb, z, outz);

  gemm_lds<<<gg, 256, 0, stream>>>(Qbf, Wob, bo, out, nullptr);
}